// Round 7
// baseline (544.662 us; speedup 1.0000x reference)
//
#include <hip/hip_runtime.h>
#include <math.h>

#define NN 20000
#define EE 320000
#define ETOT 340000   // EE + NN self-loops
#define NHEADS 8
#define HID 64
#define HCV 512       // NHEADS*HID
#define IND 128
#define OUTD 128
#define NEG_SLOPE 0.2f

typedef __attribute__((ext_vector_type(8))) short short8;
typedef __attribute__((ext_vector_type(8))) unsigned short ushort8;
typedef __attribute__((ext_vector_type(4))) float floatx4;

__device__ __forceinline__ ushort bf16_rne(float f) {
    union { float f; unsigned u; } v; v.f = f;
    unsigned u = v.u;
    unsigned r = (u + 0x7FFFu + ((u >> 16) & 1u)) >> 16;
    return (ushort)r;
}
__device__ __forceinline__ float bf16_to_f(ushort h) {
    union { unsigned u; float f; } v; v.u = ((unsigned)h) << 16;
    return v.f;
}

// ---------------- CSR build ----------------

__global__ void zero_i32(int* p, int n) {
    int i = blockIdx.x * blockDim.x + threadIdx.x;
    if (i < n) p[i] = 0;
}

__global__ void count_kernel(const int* __restrict__ ei, int* __restrict__ cnt) {
    int i = blockIdx.x * blockDim.x + threadIdx.x;
    if (i >= ETOT) return;
    int v = (i < EE) ? ei[EE + i] : (i - EE);
    atomicAdd(&cnt[v], 1);
}

// exclusive scan of cnt -> row_ptr[NN+1]; also seeds cursor = row_ptr
__global__ void scan_kernel(const int* __restrict__ cnt, int* __restrict__ row_ptr,
                            int* __restrict__ cursor) {
    __shared__ int tot[256];
    __shared__ int pre[256];
    int t = threadIdx.x;
    const int CH = (NN + 255) / 256;
    int base = t * CH;
    int s = 0;
    for (int i = 0; i < CH; i++) {
        int idx = base + i;
        if (idx < NN) s += cnt[idx];
    }
    tot[t] = s;
    __syncthreads();
    if (t == 0) {
        int run = 0;
        for (int j = 0; j < 256; j++) { pre[j] = run; run += tot[j]; }
        row_ptr[NN] = run;
    }
    __syncthreads();
    int run = pre[t];
    for (int i = 0; i < CH; i++) {
        int idx = base + i;
        if (idx < NN) { row_ptr[idx] = run; cursor[idx] = run; run += cnt[idx]; }
    }
}

__global__ void fill_kernel(const int* __restrict__ ei, int* __restrict__ cursor,
                            int* __restrict__ csr_src) {
    int i = blockIdx.x * blockDim.x + threadIdx.x;
    if (i >= ETOT) return;
    int u, v;
    if (i < EE) { u = ei[i]; v = ei[EE + i]; }
    else        { u = i - EE; v = i - EE; }
    int pos = atomicAdd(&cursor[v], 1);
    csr_src[pos] = u;
}

// ---------------- weight transpose + bf16 hi/lo split (all 3 in one launch) ----------------
__device__ __forceinline__ void cvt_one(const float* W, ushort* Thi, ushort* Tlo,
                                        int idx, int K, int N) {
    int k = idx / N, n = idx - k * N;
    float f = W[idx];
    ushort hi = bf16_rne(f);
    ushort lo = bf16_rne(f - bf16_to_f(hi));
    Thi[(size_t)n * K + k] = hi;
    Tlo[(size_t)n * K + k] = lo;
}

#define S1 (IND * HCV)
#define S2 (HCV * HCV)
#define S3 (HCV * OUTD)
__global__ void cvt_all(const float* __restrict__ W1, const float* __restrict__ W2,
                        const float* __restrict__ W3,
                        ushort* __restrict__ T1h, ushort* __restrict__ T1l,
                        ushort* __restrict__ T2h, ushort* __restrict__ T2l,
                        ushort* __restrict__ T3h, ushort* __restrict__ T3l) {
    int idx = blockIdx.x * blockDim.x + threadIdx.x;
    if (idx < S1) cvt_one(W1, T1h, T1l, idx, IND, HCV);
    else if (idx < S1 + S2) cvt_one(W2, T2h, T2l, idx - S1, HCV, HCV);
    else if (idx < S1 + S2 + S3) cvt_one(W3, T3h, T3l, idx - S1 - S2, HCV, OUTD);
}

// ---------------- MFMA GEMM 128x128 (layers 1/2): C16 = bf16(A@B), fused al ----------------
// A: fp32 [M][K] (SPLIT_A) or bf16 hi/lo [M][K]. B: transposed bf16 hi/lo [Nc][K].
// 3-term split MFMA. Epilogue: C16 bf16 store + als/ald per (row, head) plain store.
#define LDK 40
template<bool SPLIT_A>
__global__ __launch_bounds__(256) void gemm128(const void* __restrict__ Ahi_,
                                               const ushort* __restrict__ Alo,
                                               const ushort* __restrict__ Bhi,
                                               const ushort* __restrict__ Blo,
                                               ushort* __restrict__ C16,
                                               const float* __restrict__ a_src,
                                               const float* __restrict__ a_dst,
                                               float* __restrict__ als,
                                               float* __restrict__ ald,
                                               int M, int K, int Nc) {
    __shared__ ushort sA[2][128 * LDK];
    __shared__ ushort sB[2][128 * LDK];
    int tid = threadIdx.x;
    int lane = tid & 63;
    int wv = tid >> 6;
    int wr = wv >> 1, wc = wv & 1;
    int m0 = blockIdx.x * 128, n0 = blockIdx.y * 128;
    int quad = lane >> 4;
    int l15 = lane & 15;
    int arow = tid >> 2;
    int ac4 = tid & 3;

    floatx4 acc[4][4] = {};
    const ushort* Ahi = (const ushort*)Ahi_;
    const float* Af = (const float*)Ahi_;

    // staging registers
    int4 ra_h[2], ra_l[2], rb_h[2], rb_l[2];
    float4 rf0[2], rf1[2];

    auto load_tiles = [&](int k0) {
        #pragma unroll
        for (int r = 0; r < 2; r++) {
            int row = arow + r * 64;
            int gm = m0 + row;
            if (SPLIT_A) {
                if (gm < M) {
                    rf0[r] = *(const float4*)&Af[(size_t)gm * K + k0 + ac4 * 8];
                    rf1[r] = *(const float4*)&Af[(size_t)gm * K + k0 + ac4 * 8 + 4];
                } else {
                    rf0[r] = make_float4(0, 0, 0, 0); rf1[r] = rf0[r];
                }
            } else {
                if (gm < M) {
                    ra_h[r] = *(const int4*)&Ahi[(size_t)gm * K + k0 + ac4 * 8];
                    ra_l[r] = *(const int4*)&Alo[(size_t)gm * K + k0 + ac4 * 8];
                } else {
                    ra_h[r] = make_int4(0, 0, 0, 0); ra_l[r] = ra_h[r];
                }
            }
            int gn = n0 + row;
            rb_h[r] = *(const int4*)&Bhi[(size_t)gn * K + k0 + ac4 * 8];
            rb_l[r] = *(const int4*)&Blo[(size_t)gn * K + k0 + ac4 * 8];
        }
    };

    load_tiles(0);
    for (int k0 = 0; k0 < K; k0 += 32) {
        __syncthreads();
        #pragma unroll
        for (int r = 0; r < 2; r++) {
            int row = arow + r * 64;
            if (SPLIT_A) {
                float f[8] = {rf0[r].x, rf0[r].y, rf0[r].z, rf0[r].w,
                              rf1[r].x, rf1[r].y, rf1[r].z, rf1[r].w};
                ushort8 h8, l8;
                #pragma unroll
                for (int j = 0; j < 8; j++) {
                    ushort hb = bf16_rne(f[j]);
                    h8[j] = hb;
                    l8[j] = bf16_rne(f[j] - bf16_to_f(hb));
                }
                *(ushort8*)&sA[0][row * LDK + ac4 * 8] = h8;
                *(ushort8*)&sA[1][row * LDK + ac4 * 8] = l8;
            } else {
                *(int4*)&sA[0][row * LDK + ac4 * 8] = ra_h[r];
                *(int4*)&sA[1][row * LDK + ac4 * 8] = ra_l[r];
            }
            *(int4*)&sB[0][row * LDK + ac4 * 8] = rb_h[r];
            *(int4*)&sB[1][row * LDK + ac4 * 8] = rb_l[r];
        }
        __syncthreads();
        if (k0 + 32 < K) load_tiles(k0 + 32);   // prefetch overlaps MFMA below
        short8 a_hi[4], a_lo[4], b_hi[4], b_lo[4];
        #pragma unroll
        for (int i = 0; i < 4; i++) {
            int am = wr * 64 + i * 16 + l15;
            a_hi[i] = *(const short8*)&sA[0][am * LDK + quad * 8];
            a_lo[i] = *(const short8*)&sA[1][am * LDK + quad * 8];
            int bn = wc * 64 + i * 16 + l15;
            b_hi[i] = *(const short8*)&sB[0][bn * LDK + quad * 8];
            b_lo[i] = *(const short8*)&sB[1][bn * LDK + quad * 8];
        }
        #pragma unroll
        for (int i = 0; i < 4; i++)
            #pragma unroll
            for (int j = 0; j < 4; j++) {
                acc[i][j] = __builtin_amdgcn_mfma_f32_16x16x32_bf16(a_hi[i], b_hi[j], acc[i][j], 0, 0, 0);
                acc[i][j] = __builtin_amdgcn_mfma_f32_16x16x32_bf16(a_hi[i], b_lo[j], acc[i][j], 0, 0, 0);
                acc[i][j] = __builtin_amdgcn_mfma_f32_16x16x32_bf16(a_lo[i], b_hi[j], acc[i][j], 0, 0, 0);
            }
    }
    // C/D layout: col = lane&15, row = quad*4 + reg
    #pragma unroll
    for (int i = 0; i < 4; i++) {
        #pragma unroll
        for (int r = 0; r < 4; r++) {
            int gm = m0 + wr * 64 + i * 16 + quad * 4 + r;
            if (gm < M) {
                #pragma unroll
                for (int j = 0; j < 4; j++)
                    C16[(size_t)gm * Nc + n0 + wc * 64 + j * 16 + l15] = bf16_rne(acc[i][j][r]);
            }
        }
    }
    // fused attention half-logits: head hh owned entirely by this wave's columns
    int hh = (n0 + wc * 64) >> 6;
    float as_v[4], ad_v[4];
    #pragma unroll
    for (int j = 0; j < 4; j++) {
        as_v[j] = a_src[hh * HID + j * 16 + l15];
        ad_v[j] = a_dst[hh * HID + j * 16 + l15];
    }
    #pragma unroll
    for (int i = 0; i < 4; i++) {
        #pragma unroll
        for (int r = 0; r < 4; r++) {
            float ps = 0.f, pd = 0.f;
            #pragma unroll
            for (int j = 0; j < 4; j++) {
                float cv = acc[i][j][r];
                ps = fmaf(cv, as_v[j], ps);
                pd = fmaf(cv, ad_v[j], pd);
            }
            #pragma unroll
            for (int off = 1; off <= 8; off <<= 1) {
                ps += __shfl_xor(ps, off);
                pd += __shfl_xor(pd, off);
            }
            if (l15 == 0) {
                int gm = m0 + wr * 64 + i * 16 + quad * 4 + r;
                if (gm < M) {
                    als[gm * NHEADS + hh] = ps;
                    ald[gm * NHEADS + hh] = pd;
                }
            }
        }
    }
}

// ---------------- MFMA GEMM 64x128 (layer 3): fp32 C out, no al ----------------
__global__ __launch_bounds__(256) void gemm64x(const ushort* __restrict__ Ahi,
                                               const ushort* __restrict__ Alo,
                                               const ushort* __restrict__ Bhi,
                                               const ushort* __restrict__ Blo,
                                               float* __restrict__ C,
                                               int M, int K, int Nc) {
    __shared__ ushort sA[2][64 * LDK];
    __shared__ ushort sB[2][128 * LDK];
    int tid = threadIdx.x;
    int lane = tid & 63;
    int wv = tid >> 6;          // wave owns 32 cols: wv*32
    int m0 = blockIdx.x * 64;
    int quad = lane >> 4;
    int l15 = lane & 15;
    int arow = tid >> 2;        // 0..63
    int ac4 = tid & 3;

    floatx4 acc[4][2] = {};
    int4 ra_h, ra_l, rb_h[2], rb_l[2];

    auto load_tiles = [&](int k0) {
        int gm = m0 + arow;
        if (gm < M) {
            ra_h = *(const int4*)&Ahi[(size_t)gm * K + k0 + ac4 * 8];
            ra_l = *(const int4*)&Alo[(size_t)gm * K + k0 + ac4 * 8];
        } else {
            ra_h = make_int4(0, 0, 0, 0); ra_l = ra_h;
        }
        #pragma unroll
        for (int r = 0; r < 2; r++) {
            int gn = arow + r * 64;   // Nc = 128
            rb_h[r] = *(const int4*)&Bhi[(size_t)gn * K + k0 + ac4 * 8];
            rb_l[r] = *(const int4*)&Blo[(size_t)gn * K + k0 + ac4 * 8];
        }
    };

    load_tiles(0);
    for (int k0 = 0; k0 < K; k0 += 32) {
        __syncthreads();
        *(int4*)&sA[0][arow * LDK + ac4 * 8] = ra_h;
        *(int4*)&sA[1][arow * LDK + ac4 * 8] = ra_l;
        #pragma unroll
        for (int r = 0; r < 2; r++) {
            int row = arow + r * 64;
            *(int4*)&sB[0][row * LDK + ac4 * 8] = rb_h[r];
            *(int4*)&sB[1][row * LDK + ac4 * 8] = rb_l[r];
        }
        __syncthreads();
        if (k0 + 32 < K) load_tiles(k0 + 32);
        short8 a_hi[4], a_lo[4], b_hi[2], b_lo[2];
        #pragma unroll
        for (int i = 0; i < 4; i++) {
            int am = i * 16 + l15;
            a_hi[i] = *(const short8*)&sA[0][am * LDK + quad * 8];
            a_lo[i] = *(const short8*)&sA[1][am * LDK + quad * 8];
        }
        #pragma unroll
        for (int j = 0; j < 2; j++) {
            int bn = wv * 32 + j * 16 + l15;
            b_hi[j] = *(const short8*)&sB[0][bn * LDK + quad * 8];
            b_lo[j] = *(const short8*)&sB[1][bn * LDK + quad * 8];
        }
        #pragma unroll
        for (int i = 0; i < 4; i++)
            #pragma unroll
            for (int j = 0; j < 2; j++) {
                acc[i][j] = __builtin_amdgcn_mfma_f32_16x16x32_bf16(a_hi[i], b_hi[j], acc[i][j], 0, 0, 0);
                acc[i][j] = __builtin_amdgcn_mfma_f32_16x16x32_bf16(a_hi[i], b_lo[j], acc[i][j], 0, 0, 0);
                acc[i][j] = __builtin_amdgcn_mfma_f32_16x16x32_bf16(a_lo[i], b_hi[j], acc[i][j], 0, 0, 0);
            }
    }
    #pragma unroll
    for (int i = 0; i < 4; i++) {
        #pragma unroll
        for (int r = 0; r < 4; r++) {
            int gm = m0 + i * 16 + quad * 4 + r;
            if (gm < M) {
                #pragma unroll
                for (int j = 0; j < 2; j++)
                    C[(size_t)gm * Nc + wv * 32 + j * 16 + l15] = acc[i][j][r];
            }
        }
    }
}

// ---------------- layer-3 half-logits (fp32 h3) ----------------
__global__ __launch_bounds__(256) void al3_kernel(const float* __restrict__ h,
                                                  const float* __restrict__ a_src,
                                                  const float* __restrict__ a_dst,
                                                  float* __restrict__ als,
                                                  float* __restrict__ ald) {
    int lane = threadIdx.x & 63;
    int n = blockIdx.x * 4 + (threadIdx.x >> 6);
    if (n >= NN) return;
    float v0 = h[(size_t)n * OUTD + lane];
    float v1 = h[(size_t)n * OUTD + 64 + lane];
    float s = v0 * a_src[lane] + v1 * a_src[64 + lane];
    float d = v0 * a_dst[lane] + v1 * a_dst[64 + lane];
    for (int off = 32; off > 0; off >>= 1) {
        s += __shfl_down(s, off);
        d += __shfl_down(d, off);
    }
    if (lane == 0) { als[n] = s; ald[n] = d; }
}

// ---------------- fused softmax+gather (layers 1/2) ----------------
// wave per v; lane owns 8 ch (head = lane>>3). p = exp(lrelu(als+ald)) inline —
// no max subtraction (|logit| << 80; clamped for safety). No shuffles, no alpha buffer.
__global__ __launch_bounds__(256) void gather_kernel(const ushort* __restrict__ h,
                                                     const int* __restrict__ row_ptr,
                                                     const int* __restrict__ csr_src,
                                                     const float* __restrict__ als,
                                                     const float* __restrict__ ald,
                                                     const float* __restrict__ bias,
                                                     ushort* __restrict__ ghi,
                                                     ushort* __restrict__ glo) {
    int lane = threadIdx.x & 63;
    int v = blockIdx.x * 4 + (threadIdx.x >> 6);
    if (v >= NN) return;
    int hd = lane >> 3;
    float adst = ald[v * NHEADS + hd];
    int s0 = row_ptr[v], s1 = row_ptr[v + 1];
    float acc[8] = {};
    float l = 0.f;
    int i = s0;
    for (; i + 2 <= s1; i += 2) {
        int u0 = csr_src[i];
        int u1 = csr_src[i + 1];
        float t0 = als[u0 * NHEADS + hd] + adst;
        float t1 = als[u1 * NHEADS + hd] + adst;
        t0 = (t0 > 0.f) ? t0 : NEG_SLOPE * t0;
        t1 = (t1 > 0.f) ? t1 : NEG_SLOPE * t1;
        float p0 = __expf(fminf(t0, 80.f));
        float p1 = __expf(fminf(t1, 80.f));
        ushort8 x0 = *(const ushort8*)&h[(size_t)u0 * HCV + lane * 8];
        ushort8 x1 = *(const ushort8*)&h[(size_t)u1 * HCV + lane * 8];
        l += p0 + p1;
        #pragma unroll
        for (int j = 0; j < 8; j++) {
            acc[j] = fmaf(p0, bf16_to_f(x0[j]), acc[j]);
            acc[j] = fmaf(p1, bf16_to_f(x1[j]), acc[j]);
        }
    }
    if (i < s1) {
        int u0 = csr_src[i];
        float t0 = als[u0 * NHEADS + hd] + adst;
        t0 = (t0 > 0.f) ? t0 : NEG_SLOPE * t0;
        float p0 = __expf(fminf(t0, 80.f));
        ushort8 x0 = *(const ushort8*)&h[(size_t)u0 * HCV + lane * 8];
        l += p0;
        #pragma unroll
        for (int j = 0; j < 8; j++)
            acc[j] = fmaf(p0, bf16_to_f(x0[j]), acc[j]);
    }
    float inv = 1.f / (l + 1e-16f);
    ushort8 hv, lv;
    #pragma unroll
    for (int j = 0; j < 8; j++) {
        float o = fmaf(acc[j], inv, bias[lane * 8 + j]);
        o = (o > 0.f) ? o : (__expf(o) - 1.f);   // ELU
        ushort hb = bf16_rne(o);
        hv[j] = hb;
        lv[j] = bf16_rne(o - bf16_to_f(hb));
    }
    size_t idx = (size_t)v * HCV + lane * 8;
    *(ushort8*)&ghi[idx] = hv;
    *(ushort8*)&glo[idx] = lv;
}

// ---------------- fused softmax+gather, layer 3 (with max pass; fp32 h3) ----------------
__global__ __launch_bounds__(256) void gather3_kernel(const float* __restrict__ h,
                                                      const int* __restrict__ row_ptr,
                                                      const int* __restrict__ csr_src,
                                                      const float* __restrict__ als,
                                                      const float* __restrict__ ald,
                                                      const float* __restrict__ bias,
                                                      float* __restrict__ out) {
    int lane = threadIdx.x & 63;
    int v = blockIdx.x * 4 + (threadIdx.x >> 6);
    if (v >= NN) return;
    int e_sub = lane >> 5;
    int cg = lane & 31;
    float adst = ald[v];
    int s0 = row_ptr[v], s1 = row_ptr[v + 1];
    // pass 1: max logit (a_src3 has fan_in=1 -> large logits possible)
    float m = -INFINITY;
    for (int i = s0 + e_sub; i < s1; i += 2) {
        int u = csr_src[i];
        float t = als[u] + adst;
        t = (t > 0.f) ? t : NEG_SLOPE * t;
        m = fmaxf(m, t);
    }
    m = fmaxf(m, __shfl_xor(m, 32));
    // pass 2: p inline + feature accumulate
    float4 acc = make_float4(0.f, 0.f, 0.f, 0.f);
    float l = 0.f;
    for (int i = s0 + e_sub; i < s1; i += 2) {
        int u = csr_src[i];
        float t = als[u] + adst;
        t = (t > 0.f) ? t : NEG_SLOPE * t;
        float p = __expf(t - m);
        float4 x = *(const float4*)&h[(size_t)u * OUTD + cg * 4];
        l += p;
        acc.x = fmaf(p, x.x, acc.x);
        acc.y = fmaf(p, x.y, acc.y);
        acc.z = fmaf(p, x.z, acc.z);
        acc.w = fmaf(p, x.w, acc.w);
    }
    l += __shfl_xor(l, 32);
    acc.x += __shfl_xor(acc.x, 32);
    acc.y += __shfl_xor(acc.y, 32);
    acc.z += __shfl_xor(acc.z, 32);
    acc.w += __shfl_xor(acc.w, 32);
    if (e_sub == 0) {
        float inv = 1.f / (l + 1e-16f);
        float4 b4 = *(const float4*)&bias[cg * 4];
        float4 o = make_float4(fmaf(acc.x, inv, b4.x), fmaf(acc.y, inv, b4.y),
                               fmaf(acc.z, inv, b4.z), fmaf(acc.w, inv, b4.w));
        *(float4*)&out[(size_t)v * OUTD + cg * 4] = o;
    }
}

// ---------------- launch ----------------

extern "C" void kernel_launch(void* const* d_in, const int* in_sizes, int n_in,
                              void* d_out, int out_size, void* d_ws, size_t ws_size,
                              hipStream_t stream) {
    const float* x     = (const float*)d_in[0];
    const int*   ei    = (const int*)d_in[1];
    const float* W1    = (const float*)d_in[2];
    const float* as1   = (const float*)d_in[3];
    const float* ad1   = (const float*)d_in[4];
    const float* b1    = (const float*)d_in[5];
    const float* W2    = (const float*)d_in[6];
    const float* as2   = (const float*)d_in[7];
    const float* ad2   = (const float*)d_in[8];
    const float* b2    = (const float*)d_in[9];
    const float* W3    = (const float*)d_in[10];
    const float* as3   = (const float*)d_in[11];
    const float* ad3   = (const float*)d_in[12];
    const float* b3    = (const float*)d_in[13];
    float* out = (float*)d_out;

    size_t off = 0;
    auto carve = [&](size_t bytes) {
        void* p = (char*)d_ws + off;
        off += (bytes + 255) & ~(size_t)255;
        return p;
    };
    int* row_ptr  = (int*)carve((NN + 1) * sizeof(int));
    int* cursor   = (int*)carve(NN * sizeof(int));
    int* csr_src  = (int*)carve(ETOT * sizeof(int));
    ushort* hb16  = (ushort*)carve((size_t)NN * HCV * sizeof(ushort)); // pre-agg h bf16
    float* bufA   = (float*)carve((size_t)NN * OUTD * sizeof(float));  // h3 fp32
    ushort* ghi   = (ushort*)carve((size_t)NN * HCV * sizeof(ushort)); // activations hi
    ushort* glo   = (ushort*)carve((size_t)NN * HCV * sizeof(ushort)); // activations lo
    float* als    = (float*)carve((size_t)NN * NHEADS * sizeof(float));
    float* ald    = (float*)carve((size_t)NN * NHEADS * sizeof(float));
    ushort* W1Th  = (ushort*)carve((size_t)S1 * sizeof(ushort));
    ushort* W1Tl  = (ushort*)carve((size_t)S1 * sizeof(ushort));
    ushort* W2Th  = (ushort*)carve((size_t)S2 * sizeof(ushort));
    ushort* W2Tl  = (ushort*)carve((size_t)S2 * sizeof(ushort));
    ushort* W3Th  = (ushort*)carve((size_t)S3 * sizeof(ushort));
    ushort* W3Tl  = (ushort*)carve((size_t)S3 * sizeof(ushort));
    (void)ws_size; (void)n_in; (void)in_sizes; (void)out_size;

    dim3 blk(256);

    // ---- weight prep (one launch) ----
    cvt_all<<<(S1 + S2 + S3 + 255) / 256, blk, 0, stream>>>(W1, W2, W3,
        W1Th, W1Tl, W2Th, W2Tl, W3Th, W3Tl);

    // ---- CSR build (4 launches) ----
    zero_i32<<<(NN + 255) / 256, blk, 0, stream>>>(cursor, NN);
    count_kernel<<<(ETOT + 255) / 256, blk, 0, stream>>>(ei, cursor);
    scan_kernel<<<1, blk, 0, stream>>>(cursor, row_ptr, cursor);
    fill_kernel<<<(ETOT + 255) / 256, blk, 0, stream>>>(ei, cursor, csr_src);

    int mt = (NN + 127) / 128;
    int mt64 = (NN + 63) / 64;
    int nwaves_n = (NN + 3) / 4;

    // ---- layer 1 ----
    gemm128<true><<<dim3(mt, HCV / 128), blk, 0, stream>>>(x, nullptr, W1Th, W1Tl,
        hb16, as1, ad1, als, ald, NN, IND, HCV);
    gather_kernel<<<nwaves_n, blk, 0, stream>>>(hb16, row_ptr, csr_src, als, ald, b1, ghi, glo);

    // ---- layer 2 ----
    gemm128<false><<<dim3(mt, HCV / 128), blk, 0, stream>>>(ghi, glo, W2Th, W2Tl,
        hb16, as2, ad2, als, ald, NN, HCV, HCV);
    gather_kernel<<<nwaves_n, blk, 0, stream>>>(hb16, row_ptr, csr_src, als, ald, b2, ghi, glo);

    // ---- layer 3 ----
    gemm64x<<<dim3(mt64, 1), blk, 0, stream>>>(ghi, glo, W3Th, W3Tl, bufA, NN, HCV, OUTD);
    al3_kernel<<<nwaves_n, blk, 0, stream>>>(bufA, as3, ad3, als, ald);
    gather3_kernel<<<nwaves_n, blk, 0, stream>>>(bufA, row_ptr, csr_src, als, ald, b3, out);
}

// Round 8
// 419.782 us; speedup vs baseline: 1.2975x; 1.2975x over previous
//
#include <hip/hip_runtime.h>
#include <math.h>

#define NN 20000
#define EE 320000
#define ETOT 340000   // EE + NN self-loops
#define NHEADS 8
#define HID 64
#define HCV 512       // NHEADS*HID
#define IND 128
#define OUTD 128
#define NEG_SLOPE 0.2f

typedef __attribute__((ext_vector_type(8))) short short8;
typedef __attribute__((ext_vector_type(8))) unsigned short ushort8;
typedef __attribute__((ext_vector_type(4))) float floatx4;

__device__ __forceinline__ ushort bf16_rne(float f) {
    union { float f; unsigned u; } v; v.f = f;
    unsigned u = v.u;
    unsigned r = (u + 0x7FFFu + ((u >> 16) & 1u)) >> 16;
    return (ushort)r;
}
__device__ __forceinline__ float bf16_to_f(ushort h) {
    union { unsigned u; float f; } v; v.u = ((unsigned)h) << 16;
    return v.f;
}

// ---------------- CSR build ----------------

__global__ void zero_i32(int* p, int n) {
    int i = blockIdx.x * blockDim.x + threadIdx.x;
    if (i < n) p[i] = 0;
}

__global__ void count_kernel(const int* __restrict__ ei, int* __restrict__ cnt) {
    int i = blockIdx.x * blockDim.x + threadIdx.x;
    if (i >= ETOT) return;
    int v = (i < EE) ? ei[EE + i] : (i - EE);
    atomicAdd(&cnt[v], 1);
}

// exclusive scan of cnt -> row_ptr[NN+1]; also seeds cursor = row_ptr
__global__ void scan_kernel(const int* __restrict__ cnt, int* __restrict__ row_ptr,
                            int* __restrict__ cursor) {
    __shared__ int tot[256];
    __shared__ int pre[256];
    int t = threadIdx.x;
    const int CH = (NN + 255) / 256;
    int base = t * CH;
    int s = 0;
    for (int i = 0; i < CH; i++) {
        int idx = base + i;
        if (idx < NN) s += cnt[idx];
    }
    tot[t] = s;
    __syncthreads();
    if (t == 0) {
        int run = 0;
        for (int j = 0; j < 256; j++) { pre[j] = run; run += tot[j]; }
        row_ptr[NN] = run;
    }
    __syncthreads();
    int run = pre[t];
    for (int i = 0; i < CH; i++) {
        int idx = base + i;
        if (idx < NN) { row_ptr[idx] = run; cursor[idx] = run; run += cnt[idx]; }
    }
}

__global__ void fill_kernel(const int* __restrict__ ei, int* __restrict__ cursor,
                            int* __restrict__ csr_src) {
    int i = blockIdx.x * blockDim.x + threadIdx.x;
    if (i >= ETOT) return;
    int u, v;
    if (i < EE) { u = ei[i]; v = ei[EE + i]; }
    else        { u = i - EE; v = i - EE; }
    int pos = atomicAdd(&cursor[v], 1);
    csr_src[pos] = u;
}

// ---------------- weight transpose + bf16 hi/lo split (one launch) ----------------
__device__ __forceinline__ void cvt_one(const float* W, ushort* Thi, ushort* Tlo,
                                        int idx, int K, int N) {
    int k = idx / N, n = idx - k * N;
    float f = W[idx];
    ushort hi = bf16_rne(f);
    ushort lo = bf16_rne(f - bf16_to_f(hi));
    Thi[(size_t)n * K + k] = hi;
    Tlo[(size_t)n * K + k] = lo;
}

#define S1 (IND * HCV)
#define S2 (HCV * HCV)
#define S3 (HCV * OUTD)
__global__ void cvt_all(const float* __restrict__ W1, const float* __restrict__ W2,
                        const float* __restrict__ W3,
                        ushort* __restrict__ T1h, ushort* __restrict__ T1l,
                        ushort* __restrict__ T2h, ushort* __restrict__ T2l,
                        ushort* __restrict__ T3h, ushort* __restrict__ T3l) {
    int idx = blockIdx.x * blockDim.x + threadIdx.x;
    if (idx < S1) cvt_one(W1, T1h, T1l, idx, IND, HCV);
    else if (idx < S1 + S2) cvt_one(W2, T2h, T2l, idx - S1, HCV, HCV);
    else if (idx < S1 + S2 + S3) cvt_one(W3, T3h, T3l, idx - S1 - S2, HCV, OUTD);
}

// ---------------- MFMA GEMM 128x128 (layers 1/2): C16 = bf16(A@B), fused al ----------------
// Direct global->LDS staging each K-step (NO register prefetch across barriers —
// R7 showed that spills ~130B/thread/iter to scratch: WRITE_SIZE 20->343MB).
#define LDK 40
template<bool SPLIT_A>
__global__ __launch_bounds__(256) void gemm128(const void* __restrict__ Ahi_,
                                               const ushort* __restrict__ Alo,
                                               const ushort* __restrict__ Bhi,
                                               const ushort* __restrict__ Blo,
                                               ushort* __restrict__ C16,
                                               const float* __restrict__ a_src,
                                               const float* __restrict__ a_dst,
                                               float* __restrict__ als,
                                               float* __restrict__ ald,
                                               int M, int K, int Nc) {
    __shared__ ushort sA[2][128 * LDK];
    __shared__ ushort sB[2][128 * LDK];
    int tid = threadIdx.x;
    int lane = tid & 63;
    int wv = tid >> 6;
    int wr = wv >> 1, wc = wv & 1;
    int m0 = blockIdx.x * 128, n0 = blockIdx.y * 128;
    int quad = lane >> 4;
    int l15 = lane & 15;
    int arow = tid >> 2;
    int ac4 = tid & 3;

    floatx4 acc[4][4] = {};
    const ushort* Ahi = (const ushort*)Ahi_;
    const float* Af = (const float*)Ahi_;

    for (int k0 = 0; k0 < K; k0 += 32) {
        #pragma unroll
        for (int r = 0; r < 2; r++) {
            int row = arow + r * 64;
            int gm = m0 + row;
            if (SPLIT_A) {
                ushort8 h8, l8;
                if (gm < M) {
                    float4 f0 = *(const float4*)&Af[(size_t)gm * K + k0 + ac4 * 8];
                    float4 f1 = *(const float4*)&Af[(size_t)gm * K + k0 + ac4 * 8 + 4];
                    float f[8] = {f0.x, f0.y, f0.z, f0.w, f1.x, f1.y, f1.z, f1.w};
                    #pragma unroll
                    for (int j = 0; j < 8; j++) {
                        ushort hb = bf16_rne(f[j]);
                        h8[j] = hb;
                        l8[j] = bf16_rne(f[j] - bf16_to_f(hb));
                    }
                } else {
                    #pragma unroll
                    for (int j = 0; j < 8; j++) { h8[j] = 0; l8[j] = 0; }
                }
                *(ushort8*)&sA[0][row * LDK + ac4 * 8] = h8;
                *(ushort8*)&sA[1][row * LDK + ac4 * 8] = l8;
            } else {
                int4 vh, vl;
                if (gm < M) {
                    vh = *(const int4*)&Ahi[(size_t)gm * K + k0 + ac4 * 8];
                    vl = *(const int4*)&Alo[(size_t)gm * K + k0 + ac4 * 8];
                } else {
                    vh = make_int4(0, 0, 0, 0); vl = vh;
                }
                *(int4*)&sA[0][row * LDK + ac4 * 8] = vh;
                *(int4*)&sA[1][row * LDK + ac4 * 8] = vl;
            }
            int gn = n0 + row;
            int4 bh = *(const int4*)&Bhi[(size_t)gn * K + k0 + ac4 * 8];
            int4 bl = *(const int4*)&Blo[(size_t)gn * K + k0 + ac4 * 8];
            *(int4*)&sB[0][row * LDK + ac4 * 8] = bh;
            *(int4*)&sB[1][row * LDK + ac4 * 8] = bl;
        }
        __syncthreads();
        short8 a_hi[4], a_lo[4], b_hi[4], b_lo[4];
        #pragma unroll
        for (int i = 0; i < 4; i++) {
            int am = wr * 64 + i * 16 + l15;
            a_hi[i] = *(const short8*)&sA[0][am * LDK + quad * 8];
            a_lo[i] = *(const short8*)&sA[1][am * LDK + quad * 8];
            int bn = wc * 64 + i * 16 + l15;
            b_hi[i] = *(const short8*)&sB[0][bn * LDK + quad * 8];
            b_lo[i] = *(const short8*)&sB[1][bn * LDK + quad * 8];
        }
        #pragma unroll
        for (int i = 0; i < 4; i++)
            #pragma unroll
            for (int j = 0; j < 4; j++) {
                acc[i][j] = __builtin_amdgcn_mfma_f32_16x16x32_bf16(a_hi[i], b_hi[j], acc[i][j], 0, 0, 0);
                acc[i][j] = __builtin_amdgcn_mfma_f32_16x16x32_bf16(a_hi[i], b_lo[j], acc[i][j], 0, 0, 0);
                acc[i][j] = __builtin_amdgcn_mfma_f32_16x16x32_bf16(a_lo[i], b_hi[j], acc[i][j], 0, 0, 0);
            }
        __syncthreads();
    }
    // C/D layout: col = lane&15, row = quad*4 + reg
    #pragma unroll
    for (int i = 0; i < 4; i++) {
        #pragma unroll
        for (int r = 0; r < 4; r++) {
            int gm = m0 + wr * 64 + i * 16 + quad * 4 + r;
            if (gm < M) {
                #pragma unroll
                for (int j = 0; j < 4; j++)
                    C16[(size_t)gm * Nc + n0 + wc * 64 + j * 16 + l15] = bf16_rne(acc[i][j][r]);
            }
        }
    }
    // fused attention half-logits: head hh owned entirely by this wave's columns
    int hh = (n0 + wc * 64) >> 6;
    float as_v[4], ad_v[4];
    #pragma unroll
    for (int j = 0; j < 4; j++) {
        as_v[j] = a_src[hh * HID + j * 16 + l15];
        ad_v[j] = a_dst[hh * HID + j * 16 + l15];
    }
    #pragma unroll
    for (int i = 0; i < 4; i++) {
        #pragma unroll
        for (int r = 0; r < 4; r++) {
            float ps = 0.f, pd = 0.f;
            #pragma unroll
            for (int j = 0; j < 4; j++) {
                float cv = acc[i][j][r];
                ps = fmaf(cv, as_v[j], ps);
                pd = fmaf(cv, ad_v[j], pd);
            }
            #pragma unroll
            for (int off = 1; off <= 8; off <<= 1) {
                ps += __shfl_xor(ps, off);
                pd += __shfl_xor(pd, off);
            }
            if (l15 == 0) {
                int gm = m0 + wr * 64 + i * 16 + quad * 4 + r;
                if (gm < M) {
                    als[gm * NHEADS + hh] = ps;
                    ald[gm * NHEADS + hh] = pd;
                }
            }
        }
    }
}

// ---------------- MFMA GEMM 64x128 (layer 3): fp32 C out ----------------
__global__ __launch_bounds__(256) void gemm64x(const ushort* __restrict__ Ahi,
                                               const ushort* __restrict__ Alo,
                                               const ushort* __restrict__ Bhi,
                                               const ushort* __restrict__ Blo,
                                               float* __restrict__ C,
                                               int M, int K, int Nc) {
    __shared__ ushort sA[2][64 * LDK];
    __shared__ ushort sB[2][128 * LDK];
    int tid = threadIdx.x;
    int lane = tid & 63;
    int wv = tid >> 6;          // wave owns 32 cols
    int m0 = blockIdx.x * 64;
    int quad = lane >> 4;
    int l15 = lane & 15;
    int arow = tid >> 2;
    int ac4 = tid & 3;

    floatx4 acc[4][2] = {};

    for (int k0 = 0; k0 < K; k0 += 32) {
        {
            int gm = m0 + arow;
            int4 vh, vl;
            if (gm < M) {
                vh = *(const int4*)&Ahi[(size_t)gm * K + k0 + ac4 * 8];
                vl = *(const int4*)&Alo[(size_t)gm * K + k0 + ac4 * 8];
            } else {
                vh = make_int4(0, 0, 0, 0); vl = vh;
            }
            *(int4*)&sA[0][arow * LDK + ac4 * 8] = vh;
            *(int4*)&sA[1][arow * LDK + ac4 * 8] = vl;
            #pragma unroll
            for (int r = 0; r < 2; r++) {
                int gn = arow + r * 64;   // Nc = 128
                int4 bh = *(const int4*)&Bhi[(size_t)gn * K + k0 + ac4 * 8];
                int4 bl = *(const int4*)&Blo[(size_t)gn * K + k0 + ac4 * 8];
                *(int4*)&sB[0][(arow + r * 64) * LDK + ac4 * 8] = bh;
                *(int4*)&sB[1][(arow + r * 64) * LDK + ac4 * 8] = bl;
            }
        }
        __syncthreads();
        short8 a_hi[4], a_lo[4], b_hi[2], b_lo[2];
        #pragma unroll
        for (int i = 0; i < 4; i++) {
            int am = i * 16 + l15;
            a_hi[i] = *(const short8*)&sA[0][am * LDK + quad * 8];
            a_lo[i] = *(const short8*)&sA[1][am * LDK + quad * 8];
        }
        #pragma unroll
        for (int j = 0; j < 2; j++) {
            int bn = wv * 32 + j * 16 + l15;
            b_hi[j] = *(const short8*)&sB[0][bn * LDK + quad * 8];
            b_lo[j] = *(const short8*)&sB[1][bn * LDK + quad * 8];
        }
        #pragma unroll
        for (int i = 0; i < 4; i++)
            #pragma unroll
            for (int j = 0; j < 2; j++) {
                acc[i][j] = __builtin_amdgcn_mfma_f32_16x16x32_bf16(a_hi[i], b_hi[j], acc[i][j], 0, 0, 0);
                acc[i][j] = __builtin_amdgcn_mfma_f32_16x16x32_bf16(a_hi[i], b_lo[j], acc[i][j], 0, 0, 0);
                acc[i][j] = __builtin_amdgcn_mfma_f32_16x16x32_bf16(a_lo[i], b_hi[j], acc[i][j], 0, 0, 0);
            }
        __syncthreads();
    }
    #pragma unroll
    for (int i = 0; i < 4; i++) {
        #pragma unroll
        for (int r = 0; r < 4; r++) {
            int gm = m0 + i * 16 + quad * 4 + r;
            if (gm < M) {
                #pragma unroll
                for (int j = 0; j < 2; j++)
                    C[(size_t)gm * Nc + wv * 32 + j * 16 + l15] = acc[i][j][r];
            }
        }
    }
}

// ---------------- layer-3 half-logits (fp32 h3) ----------------
__global__ __launch_bounds__(256) void al3_kernel(const float* __restrict__ h,
                                                  const float* __restrict__ a_src,
                                                  const float* __restrict__ a_dst,
                                                  float* __restrict__ als,
                                                  float* __restrict__ ald) {
    int lane = threadIdx.x & 63;
    int n = blockIdx.x * 4 + (threadIdx.x >> 6);
    if (n >= NN) return;
    float v0 = h[(size_t)n * OUTD + lane];
    float v1 = h[(size_t)n * OUTD + 64 + lane];
    float s = v0 * a_src[lane] + v1 * a_src[64 + lane];
    float d = v0 * a_dst[lane] + v1 * a_dst[64 + lane];
    for (int off = 32; off > 0; off >>= 1) {
        s += __shfl_down(s, off);
        d += __shfl_down(d, off);
    }
    if (lane == 0) { als[n] = s; ald[n] = d; }
}

// ---------------- fused softmax+gather (layers 1/2) ----------------
__global__ __launch_bounds__(256) void gather_kernel(const ushort* __restrict__ h,
                                                     const int* __restrict__ row_ptr,
                                                     const int* __restrict__ csr_src,
                                                     const float* __restrict__ als,
                                                     const float* __restrict__ ald,
                                                     const float* __restrict__ bias,
                                                     ushort* __restrict__ ghi,
                                                     ushort* __restrict__ glo) {
    int lane = threadIdx.x & 63;
    int v = blockIdx.x * 4 + (threadIdx.x >> 6);
    if (v >= NN) return;
    int hd = lane >> 3;
    float adst = ald[v * NHEADS + hd];
    int s0 = row_ptr[v], s1 = row_ptr[v + 1];
    float acc[8] = {};
    float l = 0.f;
    int i = s0;
    for (; i + 2 <= s1; i += 2) {
        int u0 = csr_src[i];
        int u1 = csr_src[i + 1];
        float t0 = als[u0 * NHEADS + hd] + adst;
        float t1 = als[u1 * NHEADS + hd] + adst;
        t0 = (t0 > 0.f) ? t0 : NEG_SLOPE * t0;
        t1 = (t1 > 0.f) ? t1 : NEG_SLOPE * t1;
        float p0 = __expf(fminf(t0, 80.f));
        float p1 = __expf(fminf(t1, 80.f));
        ushort8 x0 = *(const ushort8*)&h[(size_t)u0 * HCV + lane * 8];
        ushort8 x1 = *(const ushort8*)&h[(size_t)u1 * HCV + lane * 8];
        l += p0 + p1;
        #pragma unroll
        for (int j = 0; j < 8; j++) {
            acc[j] = fmaf(p0, bf16_to_f(x0[j]), acc[j]);
            acc[j] = fmaf(p1, bf16_to_f(x1[j]), acc[j]);
        }
    }
    if (i < s1) {
        int u0 = csr_src[i];
        float t0 = als[u0 * NHEADS + hd] + adst;
        t0 = (t0 > 0.f) ? t0 : NEG_SLOPE * t0;
        float p0 = __expf(fminf(t0, 80.f));
        ushort8 x0 = *(const ushort8*)&h[(size_t)u0 * HCV + lane * 8];
        l += p0;
        #pragma unroll
        for (int j = 0; j < 8; j++)
            acc[j] = fmaf(p0, bf16_to_f(x0[j]), acc[j]);
    }
    float inv = 1.f / (l + 1e-16f);
    ushort8 hv, lv;
    #pragma unroll
    for (int j = 0; j < 8; j++) {
        float o = fmaf(acc[j], inv, bias[lane * 8 + j]);
        o = (o > 0.f) ? o : (__expf(o) - 1.f);   // ELU
        ushort hb = bf16_rne(o);
        hv[j] = hb;
        lv[j] = bf16_rne(o - bf16_to_f(hb));
    }
    size_t idx = (size_t)v * HCV + lane * 8;
    *(ushort8*)&ghi[idx] = hv;
    *(ushort8*)&glo[idx] = lv;
}

// ---------------- fused softmax+gather, layer 3 ----------------
__global__ __launch_bounds__(256) void gather3_kernel(const float* __restrict__ h,
                                                      const int* __restrict__ row_ptr,
                                                      const int* __restrict__ csr_src,
                                                      const float* __restrict__ als,
                                                      const float* __restrict__ ald,
                                                      const float* __restrict__ bias,
                                                      float* __restrict__ out) {
    int lane = threadIdx.x & 63;
    int v = blockIdx.x * 4 + (threadIdx.x >> 6);
    if (v >= NN) return;
    int e_sub = lane >> 5;
    int cg = lane & 31;
    float adst = ald[v];
    int s0 = row_ptr[v], s1 = row_ptr[v + 1];
    float m = -INFINITY;
    for (int i = s0 + e_sub; i < s1; i += 2) {
        int u = csr_src[i];
        float t = als[u] + adst;
        t = (t > 0.f) ? t : NEG_SLOPE * t;
        m = fmaxf(m, t);
    }
    m = fmaxf(m, __shfl_xor(m, 32));
    float4 acc = make_float4(0.f, 0.f, 0.f, 0.f);
    float l = 0.f;
    for (int i = s0 + e_sub; i < s1; i += 2) {
        int u = csr_src[i];
        float t = als[u] + adst;
        t = (t > 0.f) ? t : NEG_SLOPE * t;
        float p = __expf(t - m);
        float4 x = *(const float4*)&h[(size_t)u * OUTD + cg * 4];
        l += p;
        acc.x = fmaf(p, x.x, acc.x);
        acc.y = fmaf(p, x.y, acc.y);
        acc.z = fmaf(p, x.z, acc.z);
        acc.w = fmaf(p, x.w, acc.w);
    }
    l += __shfl_xor(l, 32);
    acc.x += __shfl_xor(acc.x, 32);
    acc.y += __shfl_xor(acc.y, 32);
    acc.z += __shfl_xor(acc.z, 32);
    acc.w += __shfl_xor(acc.w, 32);
    if (e_sub == 0) {
        float inv = 1.f / (l + 1e-16f);
        float4 b4 = *(const float4*)&bias[cg * 4];
        float4 o = make_float4(fmaf(acc.x, inv, b4.x), fmaf(acc.y, inv, b4.y),
                               fmaf(acc.z, inv, b4.z), fmaf(acc.w, inv, b4.w));
        *(float4*)&out[(size_t)v * OUTD + cg * 4] = o;
    }
}

// ---------------- launch ----------------

extern "C" void kernel_launch(void* const* d_in, const int* in_sizes, int n_in,
                              void* d_out, int out_size, void* d_ws, size_t ws_size,
                              hipStream_t stream) {
    const float* x     = (const float*)d_in[0];
    const int*   ei    = (const int*)d_in[1];
    const float* W1    = (const float*)d_in[2];
    const float* as1   = (const float*)d_in[3];
    const float* ad1   = (const float*)d_in[4];
    const float* b1    = (const float*)d_in[5];
    const float* W2    = (const float*)d_in[6];
    const float* as2   = (const float*)d_in[7];
    const float* ad2   = (const float*)d_in[8];
    const float* b2    = (const float*)d_in[9];
    const float* W3    = (const float*)d_in[10];
    const float* as3   = (const float*)d_in[11];
    const float* ad3   = (const float*)d_in[12];
    const float* b3    = (const float*)d_in[13];
    float* out = (float*)d_out;

    size_t off = 0;
    auto carve = [&](size_t bytes) {
        void* p = (char*)d_ws + off;
        off += (bytes + 255) & ~(size_t)255;
        return p;
    };
    int* row_ptr  = (int*)carve((NN + 1) * sizeof(int));
    int* cursor   = (int*)carve(NN * sizeof(int));
    int* csr_src  = (int*)carve(ETOT * sizeof(int));
    ushort* hb16  = (ushort*)carve((size_t)NN * HCV * sizeof(ushort)); // pre-agg h bf16
    float* bufA   = (float*)carve((size_t)NN * OUTD * sizeof(float));  // h3 fp32
    ushort* ghi   = (ushort*)carve((size_t)NN * HCV * sizeof(ushort)); // activations hi
    ushort* glo   = (ushort*)carve((size_t)NN * HCV * sizeof(ushort)); // activations lo
    float* als    = (float*)carve((size_t)NN * NHEADS * sizeof(float));
    float* ald    = (float*)carve((size_t)NN * NHEADS * sizeof(float));
    ushort* W1Th  = (ushort*)carve((size_t)S1 * sizeof(ushort));
    ushort* W1Tl  = (ushort*)carve((size_t)S1 * sizeof(ushort));
    ushort* W2Th  = (ushort*)carve((size_t)S2 * sizeof(ushort));
    ushort* W2Tl  = (ushort*)carve((size_t)S2 * sizeof(ushort));
    ushort* W3Th  = (ushort*)carve((size_t)S3 * sizeof(ushort));
    ushort* W3Tl  = (ushort*)carve((size_t)S3 * sizeof(ushort));
    (void)ws_size; (void)n_in; (void)in_sizes; (void)out_size;

    dim3 blk(256);

    // ---- weight prep (one launch) ----
    cvt_all<<<(S1 + S2 + S3 + 255) / 256, blk, 0, stream>>>(W1, W2, W3,
        W1Th, W1Tl, W2Th, W2Tl, W3Th, W3Tl);

    // ---- CSR build ----
    zero_i32<<<(NN + 255) / 256, blk, 0, stream>>>(cursor, NN);
    count_kernel<<<(ETOT + 255) / 256, blk, 0, stream>>>(ei, cursor);
    scan_kernel<<<1, blk, 0, stream>>>(cursor, row_ptr, cursor);
    fill_kernel<<<(ETOT + 255) / 256, blk, 0, stream>>>(ei, cursor, csr_src);

    int mt = (NN + 127) / 128;
    int mt64 = (NN + 63) / 64;
    int nwaves_n = (NN + 3) / 4;

    // ---- layer 1 ----
    gemm128<true><<<dim3(mt, HCV / 128), blk, 0, stream>>>(x, nullptr, W1Th, W1Tl,
        hb16, as1, ad1, als, ald, NN, IND, HCV);
    gather_kernel<<<nwaves_n, blk, 0, stream>>>(hb16, row_ptr, csr_src, als, ald, b1, ghi, glo);

    // ---- layer 2 ----
    gemm128<false><<<dim3(mt, HCV / 128), blk, 0, stream>>>(ghi, glo, W2Th, W2Tl,
        hb16, as2, ad2, als, ald, NN, HCV, HCV);
    gather_kernel<<<nwaves_n, blk, 0, stream>>>(hb16, row_ptr, csr_src, als, ald, b2, ghi, glo);

    // ---- layer 3 ----
    gemm64x<<<dim3(mt64, 1), blk, 0, stream>>>(ghi, glo, W3Th, W3Tl, bufA, NN, HCV, OUTD);
    al3_kernel<<<nwaves_n, blk, 0, stream>>>(bufA, as3, ad3, als, ald);
    gather3_kernel<<<nwaves_n, blk, 0, stream>>>(bufA, row_ptr, csr_src, als, ald, b3, out);
}

// Round 9
// 388.500 us; speedup vs baseline: 1.4020x; 1.0805x over previous
//
#include <hip/hip_runtime.h>
#include <math.h>

#define NN 20000
#define EE 320000
#define ETOT 340000   // EE + NN self-loops
#define NHEADS 8
#define HID 64
#define HCV 512       // NHEADS*HID
#define IND 128
#define OUTD 128
#define NEG_SLOPE 0.2f

typedef __attribute__((ext_vector_type(8))) short short8;
typedef __attribute__((ext_vector_type(8))) unsigned short ushort8;
typedef __attribute__((ext_vector_type(4))) float floatx4;

__device__ __forceinline__ ushort bf16_rne(float f) {
    union { float f; unsigned u; } v; v.f = f;
    unsigned u = v.u;
    unsigned r = (u + 0x7FFFu + ((u >> 16) & 1u)) >> 16;
    return (ushort)r;
}
__device__ __forceinline__ float bf16_to_f(ushort h) {
    union { unsigned u; float f; } v; v.u = ((unsigned)h) << 16;
    return v.f;
}

// ---------------- CSR build ----------------

__global__ void zero_i32(int* p, int n) {
    int i = blockIdx.x * blockDim.x + threadIdx.x;
    if (i < n) p[i] = 0;
}

__global__ void count_kernel(const int* __restrict__ ei, int* __restrict__ cnt) {
    int i = blockIdx.x * blockDim.x + threadIdx.x;
    if (i >= ETOT) return;
    int v = (i < EE) ? ei[EE + i] : (i - EE);
    atomicAdd(&cnt[v], 1);
}

// parallel single-block scan: 1024 threads, 16 waves, one global pass.
// cnt -> exclusive prefix in row_ptr[0..NN], cursor seeded = row_ptr.
#define SCH 20   // ceil(20000/1024)
__global__ __launch_bounds__(1024) void scan_kernel(const int* __restrict__ cnt,
                                                    int* __restrict__ row_ptr,
                                                    int* __restrict__ cursor) {
    __shared__ int wtot[16];
    __shared__ int woff[16];
    int t = threadIdx.x;
    int lane = t & 63;
    int wid = t >> 6;
    int base = t * SCH;
    int vals[SCH];
    int s = 0;
    #pragma unroll
    for (int i = 0; i < SCH; i++) {
        int idx = base + i;
        int v = (idx < NN) ? cnt[idx] : 0;
        vals[i] = v;
        s += v;
    }
    // wave-level inclusive scan of per-thread sums
    int incl = s;
    #pragma unroll
    for (int off = 1; off < 64; off <<= 1) {
        int u = __shfl_up(incl, off);
        if (lane >= off) incl += u;
    }
    int excl = incl - s;
    if (lane == 63) wtot[wid] = incl;
    __syncthreads();
    if (t == 0) {
        int run = 0;
        #pragma unroll
        for (int j = 0; j < 16; j++) { woff[j] = run; run += wtot[j]; }
        row_ptr[NN] = run;
    }
    __syncthreads();
    int run = woff[wid] + excl;
    #pragma unroll
    for (int i = 0; i < SCH; i++) {
        int idx = base + i;
        if (idx < NN) { row_ptr[idx] = run; cursor[idx] = run; run += vals[i]; }
    }
}

__global__ void fill_kernel(const int* __restrict__ ei, int* __restrict__ cursor,
                            int* __restrict__ csr_src) {
    int i = blockIdx.x * blockDim.x + threadIdx.x;
    if (i >= ETOT) return;
    int u, v;
    if (i < EE) { u = ei[i]; v = ei[EE + i]; }
    else        { u = i - EE; v = i - EE; }
    int pos = atomicAdd(&cursor[v], 1);
    csr_src[pos] = u;
}

// ---------------- weight transpose + bf16 hi/lo split (one launch) ----------------
__device__ __forceinline__ void cvt_one(const float* W, ushort* Thi, ushort* Tlo,
                                        int idx, int K, int N) {
    int k = idx / N, n = idx - k * N;
    float f = W[idx];
    ushort hi = bf16_rne(f);
    ushort lo = bf16_rne(f - bf16_to_f(hi));
    Thi[(size_t)n * K + k] = hi;
    Tlo[(size_t)n * K + k] = lo;
}

#define S1 (IND * HCV)
#define S2 (HCV * HCV)
#define S3 (HCV * OUTD)
__global__ void cvt_all(const float* __restrict__ W1, const float* __restrict__ W2,
                        const float* __restrict__ W3,
                        ushort* __restrict__ T1h, ushort* __restrict__ T1l,
                        ushort* __restrict__ T2h, ushort* __restrict__ T2l,
                        ushort* __restrict__ T3h, ushort* __restrict__ T3l) {
    int idx = blockIdx.x * blockDim.x + threadIdx.x;
    if (idx < S1) cvt_one(W1, T1h, T1l, idx, IND, HCV);
    else if (idx < S1 + S2) cvt_one(W2, T2h, T2l, idx - S1, HCV, HCV);
    else if (idx < S1 + S2 + S3) cvt_one(W3, T3h, T3l, idx - S1 - S2, HCV, OUTD);
}

// ---------------- MFMA GEMM 128x128 (layers 1/2): C16 = bf16(A@B), fused al ----------------
// Direct global->LDS staging each K-step (NO register prefetch across barriers —
// R7 showed that spills ~130B/thread/iter to scratch: WRITE_SIZE 20->343MB).
#define LDK 40
template<bool SPLIT_A>
__global__ __launch_bounds__(256) void gemm128(const void* __restrict__ Ahi_,
                                               const ushort* __restrict__ Alo,
                                               const ushort* __restrict__ Bhi,
                                               const ushort* __restrict__ Blo,
                                               ushort* __restrict__ C16,
                                               const float* __restrict__ a_src,
                                               const float* __restrict__ a_dst,
                                               float* __restrict__ als,
                                               float* __restrict__ ald,
                                               int M, int K, int Nc) {
    __shared__ ushort sA[2][128 * LDK];
    __shared__ ushort sB[2][128 * LDK];
    int tid = threadIdx.x;
    int lane = tid & 63;
    int wv = tid >> 6;
    int wr = wv >> 1, wc = wv & 1;
    int m0 = blockIdx.x * 128, n0 = blockIdx.y * 128;
    int quad = lane >> 4;
    int l15 = lane & 15;
    int arow = tid >> 2;
    int ac4 = tid & 3;

    floatx4 acc[4][4] = {};
    const ushort* Ahi = (const ushort*)Ahi_;
    const float* Af = (const float*)Ahi_;

    for (int k0 = 0; k0 < K; k0 += 32) {
        #pragma unroll
        for (int r = 0; r < 2; r++) {
            int row = arow + r * 64;
            int gm = m0 + row;
            if (SPLIT_A) {
                ushort8 h8, l8;
                if (gm < M) {
                    float4 f0 = *(const float4*)&Af[(size_t)gm * K + k0 + ac4 * 8];
                    float4 f1 = *(const float4*)&Af[(size_t)gm * K + k0 + ac4 * 8 + 4];
                    float f[8] = {f0.x, f0.y, f0.z, f0.w, f1.x, f1.y, f1.z, f1.w};
                    #pragma unroll
                    for (int j = 0; j < 8; j++) {
                        ushort hb = bf16_rne(f[j]);
                        h8[j] = hb;
                        l8[j] = bf16_rne(f[j] - bf16_to_f(hb));
                    }
                } else {
                    #pragma unroll
                    for (int j = 0; j < 8; j++) { h8[j] = 0; l8[j] = 0; }
                }
                *(ushort8*)&sA[0][row * LDK + ac4 * 8] = h8;
                *(ushort8*)&sA[1][row * LDK + ac4 * 8] = l8;
            } else {
                int4 vh, vl;
                if (gm < M) {
                    vh = *(const int4*)&Ahi[(size_t)gm * K + k0 + ac4 * 8];
                    vl = *(const int4*)&Alo[(size_t)gm * K + k0 + ac4 * 8];
                } else {
                    vh = make_int4(0, 0, 0, 0); vl = vh;
                }
                *(int4*)&sA[0][row * LDK + ac4 * 8] = vh;
                *(int4*)&sA[1][row * LDK + ac4 * 8] = vl;
            }
            int gn = n0 + row;
            int4 bh = *(const int4*)&Bhi[(size_t)gn * K + k0 + ac4 * 8];
            int4 bl = *(const int4*)&Blo[(size_t)gn * K + k0 + ac4 * 8];
            *(int4*)&sB[0][row * LDK + ac4 * 8] = bh;
            *(int4*)&sB[1][row * LDK + ac4 * 8] = bl;
        }
        __syncthreads();
        short8 a_hi[4], a_lo[4], b_hi[4], b_lo[4];
        #pragma unroll
        for (int i = 0; i < 4; i++) {
            int am = wr * 64 + i * 16 + l15;
            a_hi[i] = *(const short8*)&sA[0][am * LDK + quad * 8];
            a_lo[i] = *(const short8*)&sA[1][am * LDK + quad * 8];
            int bn = wc * 64 + i * 16 + l15;
            b_hi[i] = *(const short8*)&sB[0][bn * LDK + quad * 8];
            b_lo[i] = *(const short8*)&sB[1][bn * LDK + quad * 8];
        }
        #pragma unroll
        for (int i = 0; i < 4; i++)
            #pragma unroll
            for (int j = 0; j < 4; j++) {
                acc[i][j] = __builtin_amdgcn_mfma_f32_16x16x32_bf16(a_hi[i], b_hi[j], acc[i][j], 0, 0, 0);
                acc[i][j] = __builtin_amdgcn_mfma_f32_16x16x32_bf16(a_hi[i], b_lo[j], acc[i][j], 0, 0, 0);
                acc[i][j] = __builtin_amdgcn_mfma_f32_16x16x32_bf16(a_lo[i], b_hi[j], acc[i][j], 0, 0, 0);
            }
        __syncthreads();
    }
    // C/D layout: col = lane&15, row = quad*4 + reg
    #pragma unroll
    for (int i = 0; i < 4; i++) {
        #pragma unroll
        for (int r = 0; r < 4; r++) {
            int gm = m0 + wr * 64 + i * 16 + quad * 4 + r;
            if (gm < M) {
                #pragma unroll
                for (int j = 0; j < 4; j++)
                    C16[(size_t)gm * Nc + n0 + wc * 64 + j * 16 + l15] = bf16_rne(acc[i][j][r]);
            }
        }
    }
    // fused attention half-logits: head hh owned entirely by this wave's columns
    int hh = (n0 + wc * 64) >> 6;
    float as_v[4], ad_v[4];
    #pragma unroll
    for (int j = 0; j < 4; j++) {
        as_v[j] = a_src[hh * HID + j * 16 + l15];
        ad_v[j] = a_dst[hh * HID + j * 16 + l15];
    }
    #pragma unroll
    for (int i = 0; i < 4; i++) {
        #pragma unroll
        for (int r = 0; r < 4; r++) {
            float ps = 0.f, pd = 0.f;
            #pragma unroll
            for (int j = 0; j < 4; j++) {
                float cv = acc[i][j][r];
                ps = fmaf(cv, as_v[j], ps);
                pd = fmaf(cv, ad_v[j], pd);
            }
            #pragma unroll
            for (int off = 1; off <= 8; off <<= 1) {
                ps += __shfl_xor(ps, off);
                pd += __shfl_xor(pd, off);
            }
            if (l15 == 0) {
                int gm = m0 + wr * 64 + i * 16 + quad * 4 + r;
                if (gm < M) {
                    als[gm * NHEADS + hh] = ps;
                    ald[gm * NHEADS + hh] = pd;
                }
            }
        }
    }
}

// ---------------- MFMA GEMM 64x128 (layer 3): fp32 C out, fused al3 ----------------
__global__ __launch_bounds__(256) void gemm64x(const ushort* __restrict__ Ahi,
                                               const ushort* __restrict__ Alo,
                                               const ushort* __restrict__ Bhi,
                                               const ushort* __restrict__ Blo,
                                               float* __restrict__ C,
                                               const float* __restrict__ a_src,
                                               const float* __restrict__ a_dst,
                                               float* __restrict__ als,
                                               float* __restrict__ ald,
                                               int M, int K, int Nc) {
    __shared__ ushort sA[2][64 * LDK];
    __shared__ ushort sB[2][128 * LDK];
    __shared__ float psum_s[4][64];
    __shared__ float psum_d[4][64];
    int tid = threadIdx.x;
    int lane = tid & 63;
    int wv = tid >> 6;          // wave owns 32 cols
    int m0 = blockIdx.x * 64;
    int quad = lane >> 4;
    int l15 = lane & 15;
    int arow = tid >> 2;
    int ac4 = tid & 3;

    floatx4 acc[4][2] = {};

    for (int k0 = 0; k0 < K; k0 += 32) {
        {
            int gm = m0 + arow;
            int4 vh, vl;
            if (gm < M) {
                vh = *(const int4*)&Ahi[(size_t)gm * K + k0 + ac4 * 8];
                vl = *(const int4*)&Alo[(size_t)gm * K + k0 + ac4 * 8];
            } else {
                vh = make_int4(0, 0, 0, 0); vl = vh;
            }
            *(int4*)&sA[0][arow * LDK + ac4 * 8] = vh;
            *(int4*)&sA[1][arow * LDK + ac4 * 8] = vl;
            #pragma unroll
            for (int r = 0; r < 2; r++) {
                int gn = arow + r * 64;   // Nc = 128
                int4 bh = *(const int4*)&Bhi[(size_t)gn * K + k0 + ac4 * 8];
                int4 bl = *(const int4*)&Blo[(size_t)gn * K + k0 + ac4 * 8];
                *(int4*)&sB[0][(arow + r * 64) * LDK + ac4 * 8] = bh;
                *(int4*)&sB[1][(arow + r * 64) * LDK + ac4 * 8] = bl;
            }
        }
        __syncthreads();
        short8 a_hi[4], a_lo[4], b_hi[2], b_lo[2];
        #pragma unroll
        for (int i = 0; i < 4; i++) {
            int am = i * 16 + l15;
            a_hi[i] = *(const short8*)&sA[0][am * LDK + quad * 8];
            a_lo[i] = *(const short8*)&sA[1][am * LDK + quad * 8];
        }
        #pragma unroll
        for (int j = 0; j < 2; j++) {
            int bn = wv * 32 + j * 16 + l15;
            b_hi[j] = *(const short8*)&sB[0][bn * LDK + quad * 8];
            b_lo[j] = *(const short8*)&sB[1][bn * LDK + quad * 8];
        }
        #pragma unroll
        for (int i = 0; i < 4; i++)
            #pragma unroll
            for (int j = 0; j < 2; j++) {
                acc[i][j] = __builtin_amdgcn_mfma_f32_16x16x32_bf16(a_hi[i], b_hi[j], acc[i][j], 0, 0, 0);
                acc[i][j] = __builtin_amdgcn_mfma_f32_16x16x32_bf16(a_hi[i], b_lo[j], acc[i][j], 0, 0, 0);
                acc[i][j] = __builtin_amdgcn_mfma_f32_16x16x32_bf16(a_lo[i], b_hi[j], acc[i][j], 0, 0, 0);
            }
        __syncthreads();
    }
    // C store: row = i*16 + quad*4 + r, col = wv*32 + j*16 + l15
    #pragma unroll
    for (int i = 0; i < 4; i++) {
        #pragma unroll
        for (int r = 0; r < 4; r++) {
            int gm = m0 + i * 16 + quad * 4 + r;
            if (gm < M) {
                #pragma unroll
                for (int j = 0; j < 2; j++)
                    C[(size_t)gm * Nc + wv * 32 + j * 16 + l15] = acc[i][j][r];
            }
        }
    }
    // fused al3: per-lane 2-col partial, reduce over l15 (cols), then cross-wave via LDS
    float as_v[2], ad_v[2];
    #pragma unroll
    for (int j = 0; j < 2; j++) {
        as_v[j] = a_src[wv * 32 + j * 16 + l15];
        ad_v[j] = a_dst[wv * 32 + j * 16 + l15];
    }
    #pragma unroll
    for (int i = 0; i < 4; i++) {
        #pragma unroll
        for (int r = 0; r < 4; r++) {
            float ps = acc[i][0][r] * as_v[0] + acc[i][1][r] * as_v[1];
            float pd = acc[i][0][r] * ad_v[0] + acc[i][1][r] * ad_v[1];
            #pragma unroll
            for (int off = 1; off <= 8; off <<= 1) {
                ps += __shfl_xor(ps, off);
                pd += __shfl_xor(pd, off);
            }
            if (l15 == 0) {
                int row = i * 16 + quad * 4 + r;
                psum_s[wv][row] = ps;
                psum_d[wv][row] = pd;
            }
        }
    }
    __syncthreads();
    if (tid < 64) {
        int gm = m0 + tid;
        if (gm < M) {
            float s = psum_s[0][tid] + psum_s[1][tid] + psum_s[2][tid] + psum_s[3][tid];
            float d = psum_d[0][tid] + psum_d[1][tid] + psum_d[2][tid] + psum_d[3][tid];
            als[gm] = s;
            ald[gm] = d;
        }
    }
}

// ---------------- fused softmax+gather (layers 1/2) ----------------
__global__ __launch_bounds__(256) void gather_kernel(const ushort* __restrict__ h,
                                                     const int* __restrict__ row_ptr,
                                                     const int* __restrict__ csr_src,
                                                     const float* __restrict__ als,
                                                     const float* __restrict__ ald,
                                                     const float* __restrict__ bias,
                                                     ushort* __restrict__ ghi,
                                                     ushort* __restrict__ glo) {
    int lane = threadIdx.x & 63;
    int v = blockIdx.x * 4 + (threadIdx.x >> 6);
    if (v >= NN) return;
    int hd = lane >> 3;
    float adst = ald[v * NHEADS + hd];
    int s0 = row_ptr[v], s1 = row_ptr[v + 1];
    float acc[8] = {};
    float l = 0.f;
    int i = s0;
    for (; i + 2 <= s1; i += 2) {
        int u0 = csr_src[i];
        int u1 = csr_src[i + 1];
        float t0 = als[u0 * NHEADS + hd] + adst;
        float t1 = als[u1 * NHEADS + hd] + adst;
        t0 = (t0 > 0.f) ? t0 : NEG_SLOPE * t0;
        t1 = (t1 > 0.f) ? t1 : NEG_SLOPE * t1;
        float p0 = __expf(fminf(t0, 80.f));
        float p1 = __expf(fminf(t1, 80.f));
        ushort8 x0 = *(const ushort8*)&h[(size_t)u0 * HCV + lane * 8];
        ushort8 x1 = *(const ushort8*)&h[(size_t)u1 * HCV + lane * 8];
        l += p0 + p1;
        #pragma unroll
        for (int j = 0; j < 8; j++) {
            acc[j] = fmaf(p0, bf16_to_f(x0[j]), acc[j]);
            acc[j] = fmaf(p1, bf16_to_f(x1[j]), acc[j]);
        }
    }
    if (i < s1) {
        int u0 = csr_src[i];
        float t0 = als[u0 * NHEADS + hd] + adst;
        t0 = (t0 > 0.f) ? t0 : NEG_SLOPE * t0;
        float p0 = __expf(fminf(t0, 80.f));
        ushort8 x0 = *(const ushort8*)&h[(size_t)u0 * HCV + lane * 8];
        l += p0;
        #pragma unroll
        for (int j = 0; j < 8; j++)
            acc[j] = fmaf(p0, bf16_to_f(x0[j]), acc[j]);
    }
    float inv = 1.f / (l + 1e-16f);
    ushort8 hv, lv;
    #pragma unroll
    for (int j = 0; j < 8; j++) {
        float o = fmaf(acc[j], inv, bias[lane * 8 + j]);
        o = (o > 0.f) ? o : (__expf(o) - 1.f);   // ELU
        ushort hb = bf16_rne(o);
        hv[j] = hb;
        lv[j] = bf16_rne(o - bf16_to_f(hb));
    }
    size_t idx = (size_t)v * HCV + lane * 8;
    *(ushort8*)&ghi[idx] = hv;
    *(ushort8*)&glo[idx] = lv;
}

// ---------------- fused softmax+gather, layer 3 ----------------
__global__ __launch_bounds__(256) void gather3_kernel(const float* __restrict__ h,
                                                      const int* __restrict__ row_ptr,
                                                      const int* __restrict__ csr_src,
                                                      const float* __restrict__ als,
                                                      const float* __restrict__ ald,
                                                      const float* __restrict__ bias,
                                                      float* __restrict__ out) {
    int lane = threadIdx.x & 63;
    int v = blockIdx.x * 4 + (threadIdx.x >> 6);
    if (v >= NN) return;
    int e_sub = lane >> 5;
    int cg = lane & 31;
    float adst = ald[v];
    int s0 = row_ptr[v], s1 = row_ptr[v + 1];
    float m = -INFINITY;
    for (int i = s0 + e_sub; i < s1; i += 2) {
        int u = csr_src[i];
        float t = als[u] + adst;
        t = (t > 0.f) ? t : NEG_SLOPE * t;
        m = fmaxf(m, t);
    }
    m = fmaxf(m, __shfl_xor(m, 32));
    float4 acc = make_float4(0.f, 0.f, 0.f, 0.f);
    float l = 0.f;
    for (int i = s0 + e_sub; i < s1; i += 2) {
        int u = csr_src[i];
        float t = als[u] + adst;
        t = (t > 0.f) ? t : NEG_SLOPE * t;
        float p = __expf(t - m);
        float4 x = *(const float4*)&h[(size_t)u * OUTD + cg * 4];
        l += p;
        acc.x = fmaf(p, x.x, acc.x);
        acc.y = fmaf(p, x.y, acc.y);
        acc.z = fmaf(p, x.z, acc.z);
        acc.w = fmaf(p, x.w, acc.w);
    }
    l += __shfl_xor(l, 32);
    acc.x += __shfl_xor(acc.x, 32);
    acc.y += __shfl_xor(acc.y, 32);
    acc.z += __shfl_xor(acc.z, 32);
    acc.w += __shfl_xor(acc.w, 32);
    if (e_sub == 0) {
        float inv = 1.f / (l + 1e-16f);
        float4 b4 = *(const float4*)&bias[cg * 4];
        float4 o = make_float4(fmaf(acc.x, inv, b4.x), fmaf(acc.y, inv, b4.y),
                               fmaf(acc.z, inv, b4.z), fmaf(acc.w, inv, b4.w));
        *(float4*)&out[(size_t)v * OUTD + cg * 4] = o;
    }
}

// ---------------- launch ----------------

extern "C" void kernel_launch(void* const* d_in, const int* in_sizes, int n_in,
                              void* d_out, int out_size, void* d_ws, size_t ws_size,
                              hipStream_t stream) {
    const float* x     = (const float*)d_in[0];
    const int*   ei    = (const int*)d_in[1];
    const float* W1    = (const float*)d_in[2];
    const float* as1   = (const float*)d_in[3];
    const float* ad1   = (const float*)d_in[4];
    const float* b1    = (const float*)d_in[5];
    const float* W2    = (const float*)d_in[6];
    const float* as2   = (const float*)d_in[7];
    const float* ad2   = (const float*)d_in[8];
    const float* b2    = (const float*)d_in[9];
    const float* W3    = (const float*)d_in[10];
    const float* as3   = (const float*)d_in[11];
    const float* ad3   = (const float*)d_in[12];
    const float* b3    = (const float*)d_in[13];
    float* out = (float*)d_out;

    size_t off = 0;
    auto carve = [&](size_t bytes) {
        void* p = (char*)d_ws + off;
        off += (bytes + 255) & ~(size_t)255;
        return p;
    };
    int* row_ptr  = (int*)carve((NN + 1) * sizeof(int));
    int* cursor   = (int*)carve(NN * sizeof(int));
    int* csr_src  = (int*)carve(ETOT * sizeof(int));
    ushort* hb16  = (ushort*)carve((size_t)NN * HCV * sizeof(ushort)); // pre-agg h bf16
    float* bufA   = (float*)carve((size_t)NN * OUTD * sizeof(float));  // h3 fp32
    ushort* ghi   = (ushort*)carve((size_t)NN * HCV * sizeof(ushort)); // activations hi
    ushort* glo   = (ushort*)carve((size_t)NN * HCV * sizeof(ushort)); // activations lo
    float* als    = (float*)carve((size_t)NN * NHEADS * sizeof(float));
    float* ald    = (float*)carve((size_t)NN * NHEADS * sizeof(float));
    ushort* W1Th  = (ushort*)carve((size_t)S1 * sizeof(ushort));
    ushort* W1Tl  = (ushort*)carve((size_t)S1 * sizeof(ushort));
    ushort* W2Th  = (ushort*)carve((size_t)S2 * sizeof(ushort));
    ushort* W2Tl  = (ushort*)carve((size_t)S2 * sizeof(ushort));
    ushort* W3Th  = (ushort*)carve((size_t)S3 * sizeof(ushort));
    ushort* W3Tl  = (ushort*)carve((size_t)S3 * sizeof(ushort));
    (void)ws_size; (void)n_in; (void)in_sizes; (void)out_size;

    dim3 blk(256);

    // ---- weight prep (one launch) ----
    cvt_all<<<(S1 + S2 + S3 + 255) / 256, blk, 0, stream>>>(W1, W2, W3,
        W1Th, W1Tl, W2Th, W2Tl, W3Th, W3Tl);

    // ---- CSR build ----
    zero_i32<<<(NN + 255) / 256, blk, 0, stream>>>(cursor, NN);
    count_kernel<<<(ETOT + 255) / 256, blk, 0, stream>>>(ei, cursor);
    scan_kernel<<<1, 1024, 0, stream>>>(cursor, row_ptr, cursor);
    fill_kernel<<<(ETOT + 255) / 256, blk, 0, stream>>>(ei, cursor, csr_src);

    int mt = (NN + 127) / 128;
    int mt64 = (NN + 63) / 64;
    int nwaves_n = (NN + 3) / 4;

    // ---- layer 1 ----
    gemm128<true><<<dim3(mt, HCV / 128), blk, 0, stream>>>(x, nullptr, W1Th, W1Tl,
        hb16, as1, ad1, als, ald, NN, IND, HCV);
    gather_kernel<<<nwaves_n, blk, 0, stream>>>(hb16, row_ptr, csr_src, als, ald, b1, ghi, glo);

    // ---- layer 2 ----
    gemm128<false><<<dim3(mt, HCV / 128), blk, 0, stream>>>(ghi, glo, W2Th, W2Tl,
        hb16, as2, ad2, als, ald, NN, HCV, HCV);
    gather_kernel<<<nwaves_n, blk, 0, stream>>>(hb16, row_ptr, csr_src, als, ald, b2, ghi, glo);

    // ---- layer 3 (fused al3 in GEMM epilogue) ----
    gemm64x<<<dim3(mt64, 1), blk, 0, stream>>>(ghi, glo, W3Th, W3Tl, bufA,
        as3, ad3, als, ald, NN, HCV, OUTD);
    gather3_kernel<<<nwaves_n, blk, 0, stream>>>(bufA, row_ptr, csr_src, als, ald, b3, out);
}

// Round 10
// 360.345 us; speedup vs baseline: 1.5115x; 1.0781x over previous
//
#include <hip/hip_runtime.h>
#include <math.h>

#define NN 20000
#define EE 320000
#define ETOT 340000   // EE + NN self-loops
#define NHEADS 8
#define HID 64
#define HCV 512       // NHEADS*HID
#define IND 128
#define OUTD 128
#define NEG_SLOPE 0.2f

typedef __attribute__((ext_vector_type(8))) short short8;
typedef __attribute__((ext_vector_type(8))) unsigned short ushort8;
typedef __attribute__((ext_vector_type(4))) float floatx4;

__device__ __forceinline__ ushort bf16_rne(float f) {
    union { float f; unsigned u; } v; v.f = f;
    unsigned u = v.u;
    unsigned r = (u + 0x7FFFu + ((u >> 16) & 1u)) >> 16;
    return (ushort)r;
}
__device__ __forceinline__ float bf16_to_f(ushort h) {
    union { unsigned u; float f; } v; v.u = ((unsigned)h) << 16;
    return v.f;
}

// ---------------- prep: weight transpose + bf16 hi/lo split + zero cnt ----------------
__device__ __forceinline__ void cvt_one(const float* W, ushort* Thi, ushort* Tlo,
                                        int idx, int K, int N) {
    int k = idx / N, n = idx - k * N;
    float f = W[idx];
    ushort hi = bf16_rne(f);
    ushort lo = bf16_rne(f - bf16_to_f(hi));
    Thi[(size_t)n * K + k] = hi;
    Tlo[(size_t)n * K + k] = lo;
}

#define S1 (IND * HCV)
#define S2 (HCV * HCV)
#define S3 (HCV * OUTD)
#define STOT (S1 + S2 + S3)
__global__ void prep_kernel(const float* __restrict__ W1, const float* __restrict__ W2,
                            const float* __restrict__ W3,
                            ushort* __restrict__ T1h, ushort* __restrict__ T1l,
                            ushort* __restrict__ T2h, ushort* __restrict__ T2l,
                            ushort* __restrict__ T3h, ushort* __restrict__ T3l,
                            int* __restrict__ cnt) {
    int idx = blockIdx.x * blockDim.x + threadIdx.x;
    if (idx < S1) cvt_one(W1, T1h, T1l, idx, IND, HCV);
    else if (idx < S1 + S2) cvt_one(W2, T2h, T2l, idx - S1, HCV, HCV);
    else if (idx < STOT) cvt_one(W3, T3h, T3l, idx - S1 - S2, HCV, OUTD);
    else if (idx < STOT + NN) cnt[idx - STOT] = 0;
}

// ---------------- CSR build ----------------

__global__ void count_kernel(const int* __restrict__ ei, int* __restrict__ cnt) {
    int i = blockIdx.x * blockDim.x + threadIdx.x;
    if (i >= ETOT) return;
    int v = (i < EE) ? ei[EE + i] : (i - EE);
    atomicAdd(&cnt[v], 1);
}

// parallel single-block scan: 1024 threads, 16 waves, one global pass.
#define SCH 20   // ceil(20000/1024)
__global__ __launch_bounds__(1024) void scan_kernel(const int* __restrict__ cnt,
                                                    int* __restrict__ row_ptr,
                                                    int* __restrict__ cursor) {
    __shared__ int wtot[16];
    __shared__ int woff[16];
    int t = threadIdx.x;
    int lane = t & 63;
    int wid = t >> 6;
    int base = t * SCH;
    int vals[SCH];
    int s = 0;
    #pragma unroll
    for (int i = 0; i < SCH; i++) {
        int idx = base + i;
        int v = (idx < NN) ? cnt[idx] : 0;
        vals[i] = v;
        s += v;
    }
    int incl = s;
    #pragma unroll
    for (int off = 1; off < 64; off <<= 1) {
        int u = __shfl_up(incl, off);
        if (lane >= off) incl += u;
    }
    int excl = incl - s;
    if (lane == 63) wtot[wid] = incl;
    __syncthreads();
    if (t == 0) {
        int run = 0;
        #pragma unroll
        for (int j = 0; j < 16; j++) { woff[j] = run; run += wtot[j]; }
        row_ptr[NN] = run;
    }
    __syncthreads();
    int run = woff[wid] + excl;
    #pragma unroll
    for (int i = 0; i < SCH; i++) {
        int idx = base + i;
        if (idx < NN) { row_ptr[idx] = run; cursor[idx] = run; run += vals[i]; }
    }
}

__global__ void fill_kernel(const int* __restrict__ ei, int* __restrict__ cursor,
                            int* __restrict__ csr_src) {
    int i = blockIdx.x * blockDim.x + threadIdx.x;
    if (i >= ETOT) return;
    int u, v;
    if (i < EE) { u = ei[i]; v = ei[EE + i]; }
    else        { u = i - EE; v = i - EE; }
    int pos = atomicAdd(&cursor[v], 1);
    csr_src[pos] = u;
}

// ---------------- MFMA GEMM 128x128 (layers 1/2): 2-term (A bf16 x B hi/lo), fused al ----
// Direct global->LDS staging (no cross-barrier register prefetch — spills, see R7).
#define LDK 40
template<bool SPLIT_A>
__global__ __launch_bounds__(256) void gemm128(const void* __restrict__ A_,
                                               const ushort* __restrict__ Bhi,
                                               const ushort* __restrict__ Blo,
                                               ushort* __restrict__ C16,
                                               const float* __restrict__ a_src,
                                               const float* __restrict__ a_dst,
                                               float* __restrict__ als,
                                               float* __restrict__ ald,
                                               int M, int K, int Nc) {
    __shared__ ushort sA[128 * LDK];
    __shared__ ushort sB[2][128 * LDK];
    int tid = threadIdx.x;
    int lane = tid & 63;
    int wv = tid >> 6;
    int wr = wv >> 1, wc = wv & 1;
    int m0 = blockIdx.x * 128, n0 = blockIdx.y * 128;
    int quad = lane >> 4;
    int l15 = lane & 15;
    int arow = tid >> 2;
    int ac4 = tid & 3;

    floatx4 acc[4][4] = {};
    const ushort* Ab = (const ushort*)A_;
    const float* Af = (const float*)A_;

    for (int k0 = 0; k0 < K; k0 += 32) {
        #pragma unroll
        for (int r = 0; r < 2; r++) {
            int row = arow + r * 64;
            int gm = m0 + row;
            if (SPLIT_A) {
                ushort8 h8;
                if (gm < M) {
                    float4 f0 = *(const float4*)&Af[(size_t)gm * K + k0 + ac4 * 8];
                    float4 f1 = *(const float4*)&Af[(size_t)gm * K + k0 + ac4 * 8 + 4];
                    float f[8] = {f0.x, f0.y, f0.z, f0.w, f1.x, f1.y, f1.z, f1.w};
                    #pragma unroll
                    for (int j = 0; j < 8; j++) h8[j] = bf16_rne(f[j]);
                } else {
                    #pragma unroll
                    for (int j = 0; j < 8; j++) h8[j] = 0;
                }
                *(ushort8*)&sA[row * LDK + ac4 * 8] = h8;
            } else {
                int4 va;
                if (gm < M) va = *(const int4*)&Ab[(size_t)gm * K + k0 + ac4 * 8];
                else        va = make_int4(0, 0, 0, 0);
                *(int4*)&sA[row * LDK + ac4 * 8] = va;
            }
            int gn = n0 + row;
            int4 bh = *(const int4*)&Bhi[(size_t)gn * K + k0 + ac4 * 8];
            int4 bl = *(const int4*)&Blo[(size_t)gn * K + k0 + ac4 * 8];
            *(int4*)&sB[0][row * LDK + ac4 * 8] = bh;
            *(int4*)&sB[1][row * LDK + ac4 * 8] = bl;
        }
        __syncthreads();
        short8 a[4], b_hi[4], b_lo[4];
        #pragma unroll
        for (int i = 0; i < 4; i++) {
            int am = wr * 64 + i * 16 + l15;
            a[i] = *(const short8*)&sA[am * LDK + quad * 8];
            int bn = wc * 64 + i * 16 + l15;
            b_hi[i] = *(const short8*)&sB[0][bn * LDK + quad * 8];
            b_lo[i] = *(const short8*)&sB[1][bn * LDK + quad * 8];
        }
        #pragma unroll
        for (int i = 0; i < 4; i++)
            #pragma unroll
            for (int j = 0; j < 4; j++) {
                acc[i][j] = __builtin_amdgcn_mfma_f32_16x16x32_bf16(a[i], b_hi[j], acc[i][j], 0, 0, 0);
                acc[i][j] = __builtin_amdgcn_mfma_f32_16x16x32_bf16(a[i], b_lo[j], acc[i][j], 0, 0, 0);
            }
        __syncthreads();
    }
    // C/D layout: col = lane&15, row = quad*4 + reg
    #pragma unroll
    for (int i = 0; i < 4; i++) {
        #pragma unroll
        for (int r = 0; r < 4; r++) {
            int gm = m0 + wr * 64 + i * 16 + quad * 4 + r;
            if (gm < M) {
                #pragma unroll
                for (int j = 0; j < 4; j++)
                    C16[(size_t)gm * Nc + n0 + wc * 64 + j * 16 + l15] = bf16_rne(acc[i][j][r]);
            }
        }
    }
    // fused attention half-logits: head hh owned entirely by this wave's columns
    int hh = (n0 + wc * 64) >> 6;
    float as_v[4], ad_v[4];
    #pragma unroll
    for (int j = 0; j < 4; j++) {
        as_v[j] = a_src[hh * HID + j * 16 + l15];
        ad_v[j] = a_dst[hh * HID + j * 16 + l15];
    }
    #pragma unroll
    for (int i = 0; i < 4; i++) {
        #pragma unroll
        for (int r = 0; r < 4; r++) {
            float ps = 0.f, pd = 0.f;
            #pragma unroll
            for (int j = 0; j < 4; j++) {
                float cv = acc[i][j][r];
                ps = fmaf(cv, as_v[j], ps);
                pd = fmaf(cv, ad_v[j], pd);
            }
            #pragma unroll
            for (int off = 1; off <= 8; off <<= 1) {
                ps += __shfl_xor(ps, off);
                pd += __shfl_xor(pd, off);
            }
            if (l15 == 0) {
                int gm = m0 + wr * 64 + i * 16 + quad * 4 + r;
                if (gm < M) {
                    als[gm * NHEADS + hh] = ps;
                    ald[gm * NHEADS + hh] = pd;
                }
            }
        }
    }
}

// ---------------- MFMA GEMM 64x128 (layer 3): 2-term, fp32 C out, fused al3 ----------------
__global__ __launch_bounds__(256) void gemm64x(const ushort* __restrict__ A,
                                               const ushort* __restrict__ Bhi,
                                               const ushort* __restrict__ Blo,
                                               float* __restrict__ C,
                                               const float* __restrict__ a_src,
                                               const float* __restrict__ a_dst,
                                               float* __restrict__ als,
                                               float* __restrict__ ald,
                                               int M, int K, int Nc) {
    __shared__ ushort sA[64 * LDK];
    __shared__ ushort sB[2][128 * LDK];
    __shared__ float psum_s[4][64];
    __shared__ float psum_d[4][64];
    int tid = threadIdx.x;
    int lane = tid & 63;
    int wv = tid >> 6;          // wave owns 32 cols
    int m0 = blockIdx.x * 64;
    int quad = lane >> 4;
    int l15 = lane & 15;
    int arow = tid >> 2;
    int ac4 = tid & 3;

    floatx4 acc[4][2] = {};

    for (int k0 = 0; k0 < K; k0 += 32) {
        {
            int gm = m0 + arow;
            int4 va;
            if (gm < M) va = *(const int4*)&A[(size_t)gm * K + k0 + ac4 * 8];
            else        va = make_int4(0, 0, 0, 0);
            *(int4*)&sA[arow * LDK + ac4 * 8] = va;
            #pragma unroll
            for (int r = 0; r < 2; r++) {
                int gn = arow + r * 64;   // Nc = 128
                int4 bh = *(const int4*)&Bhi[(size_t)gn * K + k0 + ac4 * 8];
                int4 bl = *(const int4*)&Blo[(size_t)gn * K + k0 + ac4 * 8];
                *(int4*)&sB[0][(arow + r * 64) * LDK + ac4 * 8] = bh;
                *(int4*)&sB[1][(arow + r * 64) * LDK + ac4 * 8] = bl;
            }
        }
        __syncthreads();
        short8 a[4], b_hi[2], b_lo[2];
        #pragma unroll
        for (int i = 0; i < 4; i++) {
            int am = i * 16 + l15;
            a[i] = *(const short8*)&sA[am * LDK + quad * 8];
        }
        #pragma unroll
        for (int j = 0; j < 2; j++) {
            int bn = wv * 32 + j * 16 + l15;
            b_hi[j] = *(const short8*)&sB[0][bn * LDK + quad * 8];
            b_lo[j] = *(const short8*)&sB[1][bn * LDK + quad * 8];
        }
        #pragma unroll
        for (int i = 0; i < 4; i++)
            #pragma unroll
            for (int j = 0; j < 2; j++) {
                acc[i][j] = __builtin_amdgcn_mfma_f32_16x16x32_bf16(a[i], b_hi[j], acc[i][j], 0, 0, 0);
                acc[i][j] = __builtin_amdgcn_mfma_f32_16x16x32_bf16(a[i], b_lo[j], acc[i][j], 0, 0, 0);
            }
        __syncthreads();
    }
    #pragma unroll
    for (int i = 0; i < 4; i++) {
        #pragma unroll
        for (int r = 0; r < 4; r++) {
            int gm = m0 + i * 16 + quad * 4 + r;
            if (gm < M) {
                #pragma unroll
                for (int j = 0; j < 2; j++)
                    C[(size_t)gm * Nc + wv * 32 + j * 16 + l15] = acc[i][j][r];
            }
        }
    }
    // fused al3: per-lane 2-col partial, reduce over l15 (cols), then cross-wave via LDS
    float as_v[2], ad_v[2];
    #pragma unroll
    for (int j = 0; j < 2; j++) {
        as_v[j] = a_src[wv * 32 + j * 16 + l15];
        ad_v[j] = a_dst[wv * 32 + j * 16 + l15];
    }
    #pragma unroll
    for (int i = 0; i < 4; i++) {
        #pragma unroll
        for (int r = 0; r < 4; r++) {
            float ps = acc[i][0][r] * as_v[0] + acc[i][1][r] * as_v[1];
            float pd = acc[i][0][r] * ad_v[0] + acc[i][1][r] * ad_v[1];
            #pragma unroll
            for (int off = 1; off <= 8; off <<= 1) {
                ps += __shfl_xor(ps, off);
                pd += __shfl_xor(pd, off);
            }
            if (l15 == 0) {
                int row = i * 16 + quad * 4 + r;
                psum_s[wv][row] = ps;
                psum_d[wv][row] = pd;
            }
        }
    }
    __syncthreads();
    if (tid < 64) {
        int gm = m0 + tid;
        if (gm < M) {
            als[gm] = psum_s[0][tid] + psum_s[1][tid] + psum_s[2][tid] + psum_s[3][tid];
            ald[gm] = psum_d[0][tid] + psum_d[1][tid] + psum_d[2][tid] + psum_d[3][tid];
        }
    }
}

// ---------------- fused softmax+gather (layers 1/2), unroll 4 ----------------
__global__ __launch_bounds__(256) void gather_kernel(const ushort* __restrict__ h,
                                                     const int* __restrict__ row_ptr,
                                                     const int* __restrict__ csr_src,
                                                     const float* __restrict__ als,
                                                     const float* __restrict__ ald,
                                                     const float* __restrict__ bias,
                                                     ushort* __restrict__ gout) {
    int lane = threadIdx.x & 63;
    int v = blockIdx.x * 4 + (threadIdx.x >> 6);
    if (v >= NN) return;
    int hd = lane >> 3;
    float adst = ald[v * NHEADS + hd];
    int s0 = row_ptr[v], s1 = row_ptr[v + 1];
    float acc[8] = {};
    float l = 0.f;
    int i = s0;
    for (; i + 4 <= s1; i += 4) {
        int u0 = csr_src[i], u1 = csr_src[i + 1], u2 = csr_src[i + 2], u3 = csr_src[i + 3];
        float t0 = als[u0 * NHEADS + hd] + adst;
        float t1 = als[u1 * NHEADS + hd] + adst;
        float t2 = als[u2 * NHEADS + hd] + adst;
        float t3 = als[u3 * NHEADS + hd] + adst;
        t0 = (t0 > 0.f) ? t0 : NEG_SLOPE * t0;
        t1 = (t1 > 0.f) ? t1 : NEG_SLOPE * t1;
        t2 = (t2 > 0.f) ? t2 : NEG_SLOPE * t2;
        t3 = (t3 > 0.f) ? t3 : NEG_SLOPE * t3;
        float p0 = __expf(fminf(t0, 80.f));
        float p1 = __expf(fminf(t1, 80.f));
        float p2 = __expf(fminf(t2, 80.f));
        float p3 = __expf(fminf(t3, 80.f));
        ushort8 x0 = *(const ushort8*)&h[(size_t)u0 * HCV + lane * 8];
        ushort8 x1 = *(const ushort8*)&h[(size_t)u1 * HCV + lane * 8];
        ushort8 x2 = *(const ushort8*)&h[(size_t)u2 * HCV + lane * 8];
        ushort8 x3 = *(const ushort8*)&h[(size_t)u3 * HCV + lane * 8];
        l += (p0 + p1) + (p2 + p3);
        #pragma unroll
        for (int j = 0; j < 8; j++) {
            acc[j] = fmaf(p0, bf16_to_f(x0[j]), acc[j]);
            acc[j] = fmaf(p1, bf16_to_f(x1[j]), acc[j]);
            acc[j] = fmaf(p2, bf16_to_f(x2[j]), acc[j]);
            acc[j] = fmaf(p3, bf16_to_f(x3[j]), acc[j]);
        }
    }
    for (; i < s1; i++) {
        int u0 = csr_src[i];
        float t0 = als[u0 * NHEADS + hd] + adst;
        t0 = (t0 > 0.f) ? t0 : NEG_SLOPE * t0;
        float p0 = __expf(fminf(t0, 80.f));
        ushort8 x0 = *(const ushort8*)&h[(size_t)u0 * HCV + lane * 8];
        l += p0;
        #pragma unroll
        for (int j = 0; j < 8; j++)
            acc[j] = fmaf(p0, bf16_to_f(x0[j]), acc[j]);
    }
    float inv = 1.f / (l + 1e-16f);
    ushort8 hv;
    #pragma unroll
    for (int j = 0; j < 8; j++) {
        float o = fmaf(acc[j], inv, bias[lane * 8 + j]);
        o = (o > 0.f) ? o : (__expf(o) - 1.f);   // ELU
        hv[j] = bf16_rne(o);
    }
    *(ushort8*)&gout[(size_t)v * HCV + lane * 8] = hv;
}

// ---------------- fused softmax+gather, layer 3 ----------------
__global__ __launch_bounds__(256) void gather3_kernel(const float* __restrict__ h,
                                                      const int* __restrict__ row_ptr,
                                                      const int* __restrict__ csr_src,
                                                      const float* __restrict__ als,
                                                      const float* __restrict__ ald,
                                                      const float* __restrict__ bias,
                                                      float* __restrict__ out) {
    int lane = threadIdx.x & 63;
    int v = blockIdx.x * 4 + (threadIdx.x >> 6);
    if (v >= NN) return;
    int e_sub = lane >> 5;
    int cg = lane & 31;
    float adst = ald[v];
    int s0 = row_ptr[v], s1 = row_ptr[v + 1];
    float m = -INFINITY;
    for (int i = s0 + e_sub; i < s1; i += 2) {
        int u = csr_src[i];
        float t = als[u] + adst;
        t = (t > 0.f) ? t : NEG_SLOPE * t;
        m = fmaxf(m, t);
    }
    m = fmaxf(m, __shfl_xor(m, 32));
    float4 acc = make_float4(0.f, 0.f, 0.f, 0.f);
    float l = 0.f;
    for (int i = s0 + e_sub; i < s1; i += 2) {
        int u = csr_src[i];
        float t = als[u] + adst;
        t = (t > 0.f) ? t : NEG_SLOPE * t;
        float p = __expf(t - m);
        float4 x = *(const float4*)&h[(size_t)u * OUTD + cg * 4];
        l += p;
        acc.x = fmaf(p, x.x, acc.x);
        acc.y = fmaf(p, x.y, acc.y);
        acc.z = fmaf(p, x.z, acc.z);
        acc.w = fmaf(p, x.w, acc.w);
    }
    l += __shfl_xor(l, 32);
    acc.x += __shfl_xor(acc.x, 32);
    acc.y += __shfl_xor(acc.y, 32);
    acc.z += __shfl_xor(acc.z, 32);
    acc.w += __shfl_xor(acc.w, 32);
    if (e_sub == 0) {
        float inv = 1.f / (l + 1e-16f);
        float4 b4 = *(const float4*)&bias[cg * 4];
        float4 o = make_float4(fmaf(acc.x, inv, b4.x), fmaf(acc.y, inv, b4.y),
                               fmaf(acc.z, inv, b4.z), fmaf(acc.w, inv, b4.w));
        *(float4*)&out[(size_t)v * OUTD + cg * 4] = o;
    }
}

// ---------------- launch ----------------

extern "C" void kernel_launch(void* const* d_in, const int* in_sizes, int n_in,
                              void* d_out, int out_size, void* d_ws, size_t ws_size,
                              hipStream_t stream) {
    const float* x     = (const float*)d_in[0];
    const int*   ei    = (const int*)d_in[1];
    const float* W1    = (const float*)d_in[2];
    const float* as1   = (const float*)d_in[3];
    const float* ad1   = (const float*)d_in[4];
    const float* b1    = (const float*)d_in[5];
    const float* W2    = (const float*)d_in[6];
    const float* as2   = (const float*)d_in[7];
    const float* ad2   = (const float*)d_in[8];
    const float* b2    = (const float*)d_in[9];
    const float* W3    = (const float*)d_in[10];
    const float* as3   = (const float*)d_in[11];
    const float* ad3   = (const float*)d_in[12];
    const float* b3    = (const float*)d_in[13];
    float* out = (float*)d_out;

    size_t off = 0;
    auto carve = [&](size_t bytes) {
        void* p = (char*)d_ws + off;
        off += (bytes + 255) & ~(size_t)255;
        return p;
    };
    int* row_ptr  = (int*)carve((NN + 1) * sizeof(int));
    int* cursor   = (int*)carve(NN * sizeof(int));
    int* csr_src  = (int*)carve(ETOT * sizeof(int));
    ushort* hb16  = (ushort*)carve((size_t)NN * HCV * sizeof(ushort)); // pre-agg h bf16
    float* bufA   = (float*)carve((size_t)NN * OUTD * sizeof(float));  // h3 fp32
    ushort* gact  = (ushort*)carve((size_t)NN * HCV * sizeof(ushort)); // activations bf16
    float* als    = (float*)carve((size_t)NN * NHEADS * sizeof(float));
    float* ald    = (float*)carve((size_t)NN * NHEADS * sizeof(float));
    ushort* W1Th  = (ushort*)carve((size_t)S1 * sizeof(ushort));
    ushort* W1Tl  = (ushort*)carve((size_t)S1 * sizeof(ushort));
    ushort* W2Th  = (ushort*)carve((size_t)S2 * sizeof(ushort));
    ushort* W2Tl  = (ushort*)carve((size_t)S2 * sizeof(ushort));
    ushort* W3Th  = (ushort*)carve((size_t)S3 * sizeof(ushort));
    ushort* W3Tl  = (ushort*)carve((size_t)S3 * sizeof(ushort));
    (void)ws_size; (void)n_in; (void)in_sizes; (void)out_size;

    dim3 blk(256);

    // ---- prep: weight cvt + cnt zero (one launch) ----
    prep_kernel<<<(STOT + NN + 255) / 256, blk, 0, stream>>>(W1, W2, W3,
        W1Th, W1Tl, W2Th, W2Tl, W3Th, W3Tl, cursor);

    // ---- CSR build ----
    count_kernel<<<(ETOT + 255) / 256, blk, 0, stream>>>(ei, cursor);
    scan_kernel<<<1, 1024, 0, stream>>>(cursor, row_ptr, cursor);
    fill_kernel<<<(ETOT + 255) / 256, blk, 0, stream>>>(ei, cursor, csr_src);

    int mt = (NN + 127) / 128;
    int mt64 = (NN + 63) / 64;
    int nwaves_n = (NN + 3) / 4;

    // ---- layer 1 ----
    gemm128<true><<<dim3(mt, HCV / 128), blk, 0, stream>>>(x, W1Th, W1Tl,
        hb16, as1, ad1, als, ald, NN, IND, HCV);
    gather_kernel<<<nwaves_n, blk, 0, stream>>>(hb16, row_ptr, csr_src, als, ald, b1, gact);

    // ---- layer 2 ----
    gemm128<false><<<dim3(mt, HCV / 128), blk, 0, stream>>>(gact, W2Th, W2Tl,
        hb16, as2, ad2, als, ald, NN, HCV, HCV);
    gather_kernel<<<nwaves_n, blk, 0, stream>>>(hb16, row_ptr, csr_src, als, ald, b2, gact);

    // ---- layer 3 (fused al3 in GEMM epilogue) ----
    gemm64x<<<dim3(mt64, 1), blk, 0, stream>>>(gact, W3Th, W3Tl, bufA,
        as3, ad3, als, ald, NN, HCV, OUTD);
    gather3_kernel<<<nwaves_n, blk, 0, stream>>>(bufA, row_ptr, csr_src, als, ald, b3, out);
}

// Round 11
// 346.292 us; speedup vs baseline: 1.5728x; 1.0406x over previous
//
#include <hip/hip_runtime.h>
#include <math.h>

#define NN 20000
#define EE 320000
#define ETOT 340000   // EE + NN self-loops
#define NHEADS 8
#define HID 64
#define HCV 512       // NHEADS*HID
#define IND 128
#define OUTD 128
#define NEG_SLOPE 0.2f

typedef __attribute__((ext_vector_type(8))) _Float16 half8;
typedef __attribute__((ext_vector_type(4))) float floatx4;

// ---------------- prep: weight transpose + fp16 cvt + zero cnt ----------------
__device__ __forceinline__ void cvt_one(const float* W, _Float16* T, int idx, int K, int N) {
    int k = idx / N, n = idx - k * N;
    T[(size_t)n * K + k] = (_Float16)W[idx];
}

#define S1 (IND * HCV)
#define S2 (HCV * HCV)
#define S3 (HCV * OUTD)
#define STOT (S1 + S2 + S3)
__global__ void prep_kernel(const float* __restrict__ W1, const float* __restrict__ W2,
                            const float* __restrict__ W3,
                            _Float16* __restrict__ T1, _Float16* __restrict__ T2,
                            _Float16* __restrict__ T3, int* __restrict__ cnt) {
    int idx = blockIdx.x * blockDim.x + threadIdx.x;
    if (idx < S1) cvt_one(W1, T1, idx, IND, HCV);
    else if (idx < S1 + S2) cvt_one(W2, T2, idx - S1, HCV, HCV);
    else if (idx < STOT) cvt_one(W3, T3, idx - S1 - S2, HCV, OUTD);
    else if (idx < STOT + NN) cnt[idx - STOT] = 0;
}

// ---------------- CSR build ----------------

__global__ void count_kernel(const int* __restrict__ ei, int* __restrict__ cnt) {
    int i = blockIdx.x * blockDim.x + threadIdx.x;
    if (i >= ETOT) return;
    int v = (i < EE) ? ei[EE + i] : (i - EE);
    atomicAdd(&cnt[v], 1);
}

// parallel single-block scan: 1024 threads, 16 waves, one global pass.
#define SCH 20   // ceil(20000/1024)
__global__ __launch_bounds__(1024) void scan_kernel(const int* __restrict__ cnt,
                                                    int* __restrict__ row_ptr,
                                                    int* __restrict__ cursor) {
    __shared__ int wtot[16];
    __shared__ int woff[16];
    int t = threadIdx.x;
    int lane = t & 63;
    int wid = t >> 6;
    int base = t * SCH;
    int vals[SCH];
    int s = 0;
    #pragma unroll
    for (int i = 0; i < SCH; i++) {
        int idx = base + i;
        int v = (idx < NN) ? cnt[idx] : 0;
        vals[i] = v;
        s += v;
    }
    int incl = s;
    #pragma unroll
    for (int off = 1; off < 64; off <<= 1) {
        int u = __shfl_up(incl, off);
        if (lane >= off) incl += u;
    }
    int excl = incl - s;
    if (lane == 63) wtot[wid] = incl;
    __syncthreads();
    if (t == 0) {
        int run = 0;
        #pragma unroll
        for (int j = 0; j < 16; j++) { woff[j] = run; run += wtot[j]; }
        row_ptr[NN] = run;
    }
    __syncthreads();
    int run = woff[wid] + excl;
    #pragma unroll
    for (int i = 0; i < SCH; i++) {
        int idx = base + i;
        if (idx < NN) { row_ptr[idx] = run; cursor[idx] = run; run += vals[i]; }
    }
}

__global__ void fill_kernel(const int* __restrict__ ei, int* __restrict__ cursor,
                            int* __restrict__ csr_src) {
    int i = blockIdx.x * blockDim.x + threadIdx.x;
    if (i >= ETOT) return;
    int u, v;
    if (i < EE) { u = ei[i]; v = ei[EE + i]; }
    else        { u = i - EE; v = i - EE; }
    int pos = atomicAdd(&cursor[v], 1);
    csr_src[pos] = u;
}

// ---------------- MFMA GEMM 64x128 (layers 1/2): f16 1-term, fused al ----------------
// Grid (M/64, Nc/128): 1252 blocks (4.9/CU) vs 628 for 128-tile — grid-starvation fix.
// Direct global->LDS staging (no cross-barrier register prefetch — spills, see R7).
#define LDK 40
template<bool SPLIT_A>
__global__ __launch_bounds__(256) void gemm_l12(const void* __restrict__ A_,
                                                const _Float16* __restrict__ Bt,
                                                _Float16* __restrict__ C16,
                                                const float* __restrict__ a_src,
                                                const float* __restrict__ a_dst,
                                                float* __restrict__ als,
                                                float* __restrict__ ald,
                                                int M, int K) {
    __shared__ _Float16 sA[64 * LDK];
    __shared__ _Float16 sB[128 * LDK];
    __shared__ float psum_s[4][64];
    __shared__ float psum_d[4][64];
    int tid = threadIdx.x;
    int lane = tid & 63;
    int wv = tid >> 6;           // wave owns cols [wv*32, wv*32+32)
    int m0 = blockIdx.x * 64, n0 = blockIdx.y * 128;
    int quad = lane >> 4;
    int l15 = lane & 15;
    int arow = tid >> 2;         // 0..63
    int ac4 = tid & 3;

    floatx4 acc[4][2] = {};
    const _Float16* Ah = (const _Float16*)A_;
    const float* Af = (const float*)A_;

    for (int k0 = 0; k0 < K; k0 += 32) {
        {
            int gm = m0 + arow;
            if (SPLIT_A) {
                half8 h8;
                if (gm < M) {
                    float4 f0 = *(const float4*)&Af[(size_t)gm * K + k0 + ac4 * 8];
                    float4 f1 = *(const float4*)&Af[(size_t)gm * K + k0 + ac4 * 8 + 4];
                    float f[8] = {f0.x, f0.y, f0.z, f0.w, f1.x, f1.y, f1.z, f1.w};
                    #pragma unroll
                    for (int j = 0; j < 8; j++) h8[j] = (_Float16)f[j];
                } else {
                    #pragma unroll
                    for (int j = 0; j < 8; j++) h8[j] = (_Float16)0.f;
                }
                *(half8*)&sA[arow * LDK + ac4 * 8] = h8;
            } else {
                int4 va;
                if (gm < M) va = *(const int4*)&Ah[(size_t)gm * K + k0 + ac4 * 8];
                else        va = make_int4(0, 0, 0, 0);
                *(int4*)&sA[arow * LDK + ac4 * 8] = va;
            }
            #pragma unroll
            for (int r = 0; r < 2; r++) {
                int gn = n0 + arow + r * 64;   // Nc multiple of 128
                int4 vb = *(const int4*)&Bt[(size_t)gn * K + k0 + ac4 * 8];
                *(int4*)&sB[(arow + r * 64) * LDK + ac4 * 8] = vb;
            }
        }
        __syncthreads();
        half8 a[4], b[2];
        #pragma unroll
        for (int i = 0; i < 4; i++)
            a[i] = *(const half8*)&sA[(i * 16 + l15) * LDK + quad * 8];
        #pragma unroll
        for (int j = 0; j < 2; j++)
            b[j] = *(const half8*)&sB[(wv * 32 + j * 16 + l15) * LDK + quad * 8];
        #pragma unroll
        for (int i = 0; i < 4; i++)
            #pragma unroll
            for (int j = 0; j < 2; j++)
                acc[i][j] = __builtin_amdgcn_mfma_f32_16x16x32_f16(a[i], b[j], acc[i][j], 0, 0, 0);
        __syncthreads();
    }
    // C/D layout: col = lane&15, row = quad*4 + reg
    #pragma unroll
    for (int i = 0; i < 4; i++) {
        #pragma unroll
        for (int r = 0; r < 4; r++) {
            int gm = m0 + i * 16 + quad * 4 + r;
            if (gm < M) {
                #pragma unroll
                for (int j = 0; j < 2; j++)
                    C16[(size_t)gm * HCV + n0 + wv * 32 + j * 16 + l15] = (_Float16)acc[i][j][r];
            }
        }
    }
    // fused attention half-logits: wave's 32 cols lie in one head (head = wv>>1 local)
    int h0 = n0 >> 6;            // first head of this block's 128 cols
    float as_v[2], ad_v[2];
    #pragma unroll
    for (int j = 0; j < 2; j++) {
        int dim = (wv * 32 + j * 16 + l15) & 63;
        int hh = h0 + (wv >> 1);
        as_v[j] = a_src[hh * HID + dim];
        ad_v[j] = a_dst[hh * HID + dim];
    }
    #pragma unroll
    for (int i = 0; i < 4; i++) {
        #pragma unroll
        for (int r = 0; r < 4; r++) {
            float ps = acc[i][0][r] * as_v[0] + acc[i][1][r] * as_v[1];
            float pd = acc[i][0][r] * ad_v[0] + acc[i][1][r] * ad_v[1];
            #pragma unroll
            for (int off = 1; off <= 8; off <<= 1) {
                ps += __shfl_xor(ps, off);
                pd += __shfl_xor(pd, off);
            }
            if (l15 == 0) {
                int row = i * 16 + quad * 4 + r;
                psum_s[wv][row] = ps;
                psum_d[wv][row] = pd;
            }
        }
    }
    __syncthreads();
    if (tid < 64) {
        int gm = m0 + tid;
        if (gm < M) {
            als[gm * NHEADS + h0]     = psum_s[0][tid] + psum_s[1][tid];
            als[gm * NHEADS + h0 + 1] = psum_s[2][tid] + psum_s[3][tid];
            ald[gm * NHEADS + h0]     = psum_d[0][tid] + psum_d[1][tid];
            ald[gm * NHEADS + h0 + 1] = psum_d[2][tid] + psum_d[3][tid];
        }
    }
}

// ---------------- MFMA GEMM 64x128 (layer 3): f16 1-term, fp32 C out, fused al3 ----------------
__global__ __launch_bounds__(256) void gemm3(const _Float16* __restrict__ A,
                                             const _Float16* __restrict__ Bt,
                                             float* __restrict__ C,
                                             const float* __restrict__ a_src,
                                             const float* __restrict__ a_dst,
                                             float* __restrict__ als,
                                             float* __restrict__ ald,
                                             int M, int K) {
    __shared__ _Float16 sA[64 * LDK];
    __shared__ _Float16 sB[128 * LDK];
    __shared__ float psum_s[4][64];
    __shared__ float psum_d[4][64];
    int tid = threadIdx.x;
    int lane = tid & 63;
    int wv = tid >> 6;
    int m0 = blockIdx.x * 64;
    int quad = lane >> 4;
    int l15 = lane & 15;
    int arow = tid >> 2;
    int ac4 = tid & 3;

    floatx4 acc[4][2] = {};

    for (int k0 = 0; k0 < K; k0 += 32) {
        {
            int gm = m0 + arow;
            int4 va;
            if (gm < M) va = *(const int4*)&A[(size_t)gm * K + k0 + ac4 * 8];
            else        va = make_int4(0, 0, 0, 0);
            *(int4*)&sA[arow * LDK + ac4 * 8] = va;
            #pragma unroll
            for (int r = 0; r < 2; r++) {
                int gn = arow + r * 64;   // Nc = 128
                int4 vb = *(const int4*)&Bt[(size_t)gn * K + k0 + ac4 * 8];
                *(int4*)&sB[(arow + r * 64) * LDK + ac4 * 8] = vb;
            }
        }
        __syncthreads();
        half8 a[4], b[2];
        #pragma unroll
        for (int i = 0; i < 4; i++)
            a[i] = *(const half8*)&sA[(i * 16 + l15) * LDK + quad * 8];
        #pragma unroll
        for (int j = 0; j < 2; j++)
            b[j] = *(const half8*)&sB[(wv * 32 + j * 16 + l15) * LDK + quad * 8];
        #pragma unroll
        for (int i = 0; i < 4; i++)
            #pragma unroll
            for (int j = 0; j < 2; j++)
                acc[i][j] = __builtin_amdgcn_mfma_f32_16x16x32_f16(a[i], b[j], acc[i][j], 0, 0, 0);
        __syncthreads();
    }
    #pragma unroll
    for (int i = 0; i < 4; i++) {
        #pragma unroll
        for (int r = 0; r < 4; r++) {
            int gm = m0 + i * 16 + quad * 4 + r;
            if (gm < M) {
                #pragma unroll
                for (int j = 0; j < 2; j++)
                    C[(size_t)gm * OUTD + wv * 32 + j * 16 + l15] = acc[i][j][r];
            }
        }
    }
    // fused al3 (single 128-dim head): all 4 waves combine
    float as_v[2], ad_v[2];
    #pragma unroll
    for (int j = 0; j < 2; j++) {
        as_v[j] = a_src[wv * 32 + j * 16 + l15];
        ad_v[j] = a_dst[wv * 32 + j * 16 + l15];
    }
    #pragma unroll
    for (int i = 0; i < 4; i++) {
        #pragma unroll
        for (int r = 0; r < 4; r++) {
            float ps = acc[i][0][r] * as_v[0] + acc[i][1][r] * as_v[1];
            float pd = acc[i][0][r] * ad_v[0] + acc[i][1][r] * ad_v[1];
            #pragma unroll
            for (int off = 1; off <= 8; off <<= 1) {
                ps += __shfl_xor(ps, off);
                pd += __shfl_xor(pd, off);
            }
            if (l15 == 0) {
                int row = i * 16 + quad * 4 + r;
                psum_s[wv][row] = ps;
                psum_d[wv][row] = pd;
            }
        }
    }
    __syncthreads();
    if (tid < 64) {
        int gm = m0 + tid;
        if (gm < M) {
            als[gm] = psum_s[0][tid] + psum_s[1][tid] + psum_s[2][tid] + psum_s[3][tid];
            ald[gm] = psum_d[0][tid] + psum_d[1][tid] + psum_d[2][tid] + psum_d[3][tid];
        }
    }
}

// ---------------- fused softmax+gather (layers 1/2), fp16 h, unroll 4 ----------------
__global__ __launch_bounds__(256) void gather_kernel(const _Float16* __restrict__ h,
                                                     const int* __restrict__ row_ptr,
                                                     const int* __restrict__ csr_src,
                                                     const float* __restrict__ als,
                                                     const float* __restrict__ ald,
                                                     const float* __restrict__ bias,
                                                     _Float16* __restrict__ gout) {
    int lane = threadIdx.x & 63;
    int v = blockIdx.x * 4 + (threadIdx.x >> 6);
    if (v >= NN) return;
    int hd = lane >> 3;
    float adst = ald[v * NHEADS + hd];
    int s0 = row_ptr[v], s1 = row_ptr[v + 1];
    float acc[8] = {};
    float l = 0.f;
    int i = s0;
    for (; i + 4 <= s1; i += 4) {
        int u0 = csr_src[i], u1 = csr_src[i + 1], u2 = csr_src[i + 2], u3 = csr_src[i + 3];
        float t0 = als[u0 * NHEADS + hd] + adst;
        float t1 = als[u1 * NHEADS + hd] + adst;
        float t2 = als[u2 * NHEADS + hd] + adst;
        float t3 = als[u3 * NHEADS + hd] + adst;
        t0 = (t0 > 0.f) ? t0 : NEG_SLOPE * t0;
        t1 = (t1 > 0.f) ? t1 : NEG_SLOPE * t1;
        t2 = (t2 > 0.f) ? t2 : NEG_SLOPE * t2;
        t3 = (t3 > 0.f) ? t3 : NEG_SLOPE * t3;
        float p0 = __expf(fminf(t0, 80.f));
        float p1 = __expf(fminf(t1, 80.f));
        float p2 = __expf(fminf(t2, 80.f));
        float p3 = __expf(fminf(t3, 80.f));
        half8 x0 = *(const half8*)&h[(size_t)u0 * HCV + lane * 8];
        half8 x1 = *(const half8*)&h[(size_t)u1 * HCV + lane * 8];
        half8 x2 = *(const half8*)&h[(size_t)u2 * HCV + lane * 8];
        half8 x3 = *(const half8*)&h[(size_t)u3 * HCV + lane * 8];
        l += (p0 + p1) + (p2 + p3);
        #pragma unroll
        for (int j = 0; j < 8; j++) {
            acc[j] = fmaf(p0, (float)x0[j], acc[j]);
            acc[j] = fmaf(p1, (float)x1[j], acc[j]);
            acc[j] = fmaf(p2, (float)x2[j], acc[j]);
            acc[j] = fmaf(p3, (float)x3[j], acc[j]);
        }
    }
    for (; i < s1; i++) {
        int u0 = csr_src[i];
        float t0 = als[u0 * NHEADS + hd] + adst;
        t0 = (t0 > 0.f) ? t0 : NEG_SLOPE * t0;
        float p0 = __expf(fminf(t0, 80.f));
        half8 x0 = *(const half8*)&h[(size_t)u0 * HCV + lane * 8];
        l += p0;
        #pragma unroll
        for (int j = 0; j < 8; j++)
            acc[j] = fmaf(p0, (float)x0[j], acc[j]);
    }
    float inv = 1.f / (l + 1e-16f);
    half8 hv;
    #pragma unroll
    for (int j = 0; j < 8; j++) {
        float o = fmaf(acc[j], inv, bias[lane * 8 + j]);
        o = (o > 0.f) ? o : (__expf(o) - 1.f);   // ELU
        hv[j] = (_Float16)o;
    }
    *(half8*)&gout[(size_t)v * HCV + lane * 8] = hv;
}

// ---------------- fused softmax+gather, layer 3 (fp32 h3 -> fp32 out) ----------------
__global__ __launch_bounds__(256) void gather3_kernel(const float* __restrict__ h,
                                                      const int* __restrict__ row_ptr,
                                                      const int* __restrict__ csr_src,
                                                      const float* __restrict__ als,
                                                      const float* __restrict__ ald,
                                                      const float* __restrict__ bias,
                                                      float* __restrict__ out) {
    int lane = threadIdx.x & 63;
    int v = blockIdx.x * 4 + (threadIdx.x >> 6);
    if (v >= NN) return;
    int e_sub = lane >> 5;
    int cg = lane & 31;
    float adst = ald[v];
    int s0 = row_ptr[v], s1 = row_ptr[v + 1];
    float m = -INFINITY;
    for (int i = s0 + e_sub; i < s1; i += 2) {
        int u = csr_src[i];
        float t = als[u] + adst;
        t = (t > 0.f) ? t : NEG_SLOPE * t;
        m = fmaxf(m, t);
    }
    m = fmaxf(m, __shfl_xor(m, 32));
    float4 acc = make_float4(0.f, 0.f, 0.f, 0.f);
    float l = 0.f;
    for (int i = s0 + e_sub; i < s1; i += 2) {
        int u = csr_src[i];
        float t = als[u] + adst;
        t = (t > 0.f) ? t : NEG_SLOPE * t;
        float p = __expf(t - m);
        float4 x = *(const float4*)&h[(size_t)u * OUTD + cg * 4];
        l += p;
        acc.x = fmaf(p, x.x, acc.x);
        acc.y = fmaf(p, x.y, acc.y);
        acc.z = fmaf(p, x.z, acc.z);
        acc.w = fmaf(p, x.w, acc.w);
    }
    l += __shfl_xor(l, 32);
    acc.x += __shfl_xor(acc.x, 32);
    acc.y += __shfl_xor(acc.y, 32);
    acc.z += __shfl_xor(acc.z, 32);
    acc.w += __shfl_xor(acc.w, 32);
    if (e_sub == 0) {
        float inv = 1.f / (l + 1e-16f);
        float4 b4 = *(const float4*)&bias[cg * 4];
        float4 o = make_float4(fmaf(acc.x, inv, b4.x), fmaf(acc.y, inv, b4.y),
                               fmaf(acc.z, inv, b4.z), fmaf(acc.w, inv, b4.w));
        *(float4*)&out[(size_t)v * OUTD + cg * 4] = o;
    }
}

// ---------------- launch ----------------

extern "C" void kernel_launch(void* const* d_in, const int* in_sizes, int n_in,
                              void* d_out, int out_size, void* d_ws, size_t ws_size,
                              hipStream_t stream) {
    const float* x     = (const float*)d_in[0];
    const int*   ei    = (const int*)d_in[1];
    const float* W1    = (const float*)d_in[2];
    const float* as1   = (const float*)d_in[3];
    const float* ad1   = (const float*)d_in[4];
    const float* b1    = (const float*)d_in[5];
    const float* W2    = (const float*)d_in[6];
    const float* as2   = (const float*)d_in[7];
    const float* ad2   = (const float*)d_in[8];
    const float* b2    = (const float*)d_in[9];
    const float* W3    = (const float*)d_in[10];
    const float* as3   = (const float*)d_in[11];
    const float* ad3   = (const float*)d_in[12];
    const float* b3    = (const float*)d_in[13];
    float* out = (float*)d_out;

    size_t off = 0;
    auto carve = [&](size_t bytes) {
        void* p = (char*)d_ws + off;
        off += (bytes + 255) & ~(size_t)255;
        return p;
    };
    int* row_ptr   = (int*)carve((NN + 1) * sizeof(int));
    int* cursor    = (int*)carve(NN * sizeof(int));
    int* csr_src   = (int*)carve(ETOT * sizeof(int));
    _Float16* hf16 = (_Float16*)carve((size_t)NN * HCV * sizeof(_Float16)); // pre-agg h
    float* bufA    = (float*)carve((size_t)NN * OUTD * sizeof(float));      // h3 fp32
    _Float16* gact = (_Float16*)carve((size_t)NN * HCV * sizeof(_Float16)); // activations
    float* als     = (float*)carve((size_t)NN * NHEADS * sizeof(float));
    float* ald     = (float*)carve((size_t)NN * NHEADS * sizeof(float));
    _Float16* W1T  = (_Float16*)carve((size_t)S1 * sizeof(_Float16));
    _Float16* W2T  = (_Float16*)carve((size_t)S2 * sizeof(_Float16));
    _Float16* W3T  = (_Float16*)carve((size_t)S3 * sizeof(_Float16));
    (void)ws_size; (void)n_in; (void)in_sizes; (void)out_size;

    dim3 blk(256);

    // ---- prep: weight cvt + cnt zero (one launch) ----
    prep_kernel<<<(STOT + NN + 255) / 256, blk, 0, stream>>>(W1, W2, W3,
        W1T, W2T, W3T, cursor);

    // ---- CSR build ----
    count_kernel<<<(ETOT + 255) / 256, blk, 0, stream>>>(ei, cursor);
    scan_kernel<<<1, 1024, 0, stream>>>(cursor, row_ptr, cursor);
    fill_kernel<<<(ETOT + 255) / 256, blk, 0, stream>>>(ei, cursor, csr_src);

    int mt64 = (NN + 63) / 64;
    int nwaves_n = (NN + 3) / 4;

    // ---- layer 1 ----
    gemm_l12<true><<<dim3(mt64, HCV / 128), blk, 0, stream>>>(x, W1T,
        hf16, as1, ad1, als, ald, NN, IND);
    gather_kernel<<<nwaves_n, blk, 0, stream>>>(hf16, row_ptr, csr_src, als, ald, b1, gact);

    // ---- layer 2 ----
    gemm_l12<false><<<dim3(mt64, HCV / 128), blk, 0, stream>>>(gact, W2T,
        hf16, as2, ad2, als, ald, NN, HCV);
    gather_kernel<<<nwaves_n, blk, 0, stream>>>(hf16, row_ptr, csr_src, als, ald, b2, gact);

    // ---- layer 3 ----
    gemm3<<<dim3(mt64, 1), blk, 0, stream>>>(gact, W3T, bufA,
        as3, ad3, als, ald, NN, HCV);
    gather3_kernel<<<nwaves_n, blk, 0, stream>>>(bufA, row_ptr, csr_src, als, ald, b3, out);
}

// Round 12
// 346.280 us; speedup vs baseline: 1.5729x; 1.0000x over previous
//
#include <hip/hip_runtime.h>
#include <math.h>

#define NN 20000
#define EE 320000
#define ETOT 340000   // EE + NN self-loops
#define NHEADS 8
#define HID 64
#define HCV 512       // NHEADS*HID
#define IND 128
#define OUTD 128
#define NEG_SLOPE 0.2f

typedef __attribute__((ext_vector_type(8))) _Float16 half8;
typedef __attribute__((ext_vector_type(4))) float floatx4;

// ---------------- prep: W cvt + x cvt + w1 projection + zero cnt ----------------
__device__ __forceinline__ void cvt_one(const float* W, _Float16* T, int idx, int K, int N) {
    int k = idx / N, n = idx - k * N;
    T[(size_t)n * K + k] = (_Float16)W[idx];
}

#define S1 (IND * HCV)
#define S2 (HCV * HCV)
#define S3 (HCV * OUTD)
#define STOT (S1 + S2 + S3)
#define XTOT (NN * IND)
// ranges: [0,S1) W1 | [S1,S1+S2) W2 | [..,STOT) W3 | +NN cnt | +XTOT x cvt | +2048 w1p
__global__ void prep_kernel(const float* __restrict__ W1, const float* __restrict__ W2,
                            const float* __restrict__ W3, const float* __restrict__ x,
                            const float* __restrict__ as1, const float* __restrict__ ad1,
                            _Float16* __restrict__ T1, _Float16* __restrict__ T2,
                            _Float16* __restrict__ T3, _Float16* __restrict__ xh,
                            float* __restrict__ w1p, int* __restrict__ cnt) {
    int idx = blockIdx.x * blockDim.x + threadIdx.x;
    if (idx < S1) cvt_one(W1, T1, idx, IND, HCV);
    else if (idx < S1 + S2) cvt_one(W2, T2, idx - S1, HCV, HCV);
    else if (idx < STOT) cvt_one(W3, T3, idx - S1 - S2, HCV, OUTD);
    else if (idx < STOT + NN) cnt[idx - STOT] = 0;
    else if (idx < STOT + NN + XTOT) {
        int j = idx - STOT - NN;
        xh[j] = (_Float16)x[j];
    } else if (idx < STOT + NN + XTOT + IND * 16) {
        int j = idx - STOT - NN - XTOT;
        int c = j >> 4, o = j & 15;
        int hh = o & 7;
        const float* av = (o < 8) ? as1 : ad1;
        float s = 0.f;
        #pragma unroll 8
        for (int jj = 0; jj < HID; jj++)
            s = fmaf(W1[c * HCV + hh * HID + jj], av[hh * HID + jj], s);
        w1p[c * 16 + o] = s;
    }
}

// ---------------- CSR build ----------------

__global__ void count_kernel(const int* __restrict__ ei, int* __restrict__ cnt) {
    int i = blockIdx.x * blockDim.x + threadIdx.x;
    if (i >= ETOT) return;
    int v = (i < EE) ? ei[EE + i] : (i - EE);
    atomicAdd(&cnt[v], 1);
}

#define SCH 20   // ceil(20000/1024)
__global__ __launch_bounds__(1024) void scan_kernel(const int* __restrict__ cnt,
                                                    int* __restrict__ row_ptr,
                                                    int* __restrict__ cursor) {
    __shared__ int wtot[16];
    __shared__ int woff[16];
    int t = threadIdx.x;
    int lane = t & 63;
    int wid = t >> 6;
    int base = t * SCH;
    int vals[SCH];
    int s = 0;
    #pragma unroll
    for (int i = 0; i < SCH; i++) {
        int idx = base + i;
        int v = (idx < NN) ? cnt[idx] : 0;
        vals[i] = v;
        s += v;
    }
    int incl = s;
    #pragma unroll
    for (int off = 1; off < 64; off <<= 1) {
        int u = __shfl_up(incl, off);
        if (lane >= off) incl += u;
    }
    int excl = incl - s;
    if (lane == 63) wtot[wid] = incl;
    __syncthreads();
    if (t == 0) {
        int run = 0;
        #pragma unroll
        for (int j = 0; j < 16; j++) { woff[j] = run; run += wtot[j]; }
        row_ptr[NN] = run;
    }
    __syncthreads();
    int run = woff[wid] + excl;
    #pragma unroll
    for (int i = 0; i < SCH; i++) {
        int idx = base + i;
        if (idx < NN) { row_ptr[idx] = run; cursor[idx] = run; run += vals[i]; }
    }
}

__global__ void fill_kernel(const int* __restrict__ ei, int* __restrict__ cursor,
                            int* __restrict__ csr_src) {
    int i = blockIdx.x * blockDim.x + threadIdx.x;
    if (i >= ETOT) return;
    int u, v;
    if (i < EE) { u = ei[i]; v = ei[EE + i]; }
    else        { u = i - EE; v = i - EE; }
    int pos = atomicAdd(&cursor[v], 1);
    csr_src[pos] = u;
}

// ---------------- layer-1 half-logits from x (thin dot) ----------------
__global__ void al1_thin(const float* __restrict__ x, const float* __restrict__ w1p,
                         float* __restrict__ als, float* __restrict__ ald) {
    int gid = blockIdx.x * blockDim.x + threadIdx.x;
    int node = gid >> 4, o = gid & 15;
    if (node >= NN) return;
    const float* xr = x + (size_t)node * IND;
    float s = 0.f;
    #pragma unroll 4
    for (int c = 0; c < IND; c++)
        s = fmaf(xr[c], w1p[c * 16 + o], s);
    if (o < 8) als[node * 8 + o] = s;
    else       ald[node * 8 + (o - 8)] = s;
}

// ---------------- layer-1 gather: per-head aggregation of 128-dim x (fp16) ----------------
// wave per v; lane = head(0..7)*8 + cg(0..7); lane owns 16 ch of its head's aggregate.
// xagg layout: [NN][8][128] f16.
__global__ __launch_bounds__(256) void gather1_kernel(const _Float16* __restrict__ xh,
                                                      const int* __restrict__ row_ptr,
                                                      const int* __restrict__ csr_src,
                                                      const float* __restrict__ als,
                                                      const float* __restrict__ ald,
                                                      _Float16* __restrict__ xagg) {
    int lane = threadIdx.x & 63;
    int v = blockIdx.x * 4 + (threadIdx.x >> 6);
    if (v >= NN) return;
    int hd = lane >> 3;
    int cg = lane & 7;        // 16 channels: cg*16
    float adst = ald[v * NHEADS + hd];
    int s0 = row_ptr[v], s1 = row_ptr[v + 1];
    float acc[16] = {};
    float l = 0.f;
    int i = s0;
    for (; i + 2 <= s1; i += 2) {
        int u0 = csr_src[i], u1 = csr_src[i + 1];
        float t0 = als[u0 * NHEADS + hd] + adst;
        float t1 = als[u1 * NHEADS + hd] + adst;
        t0 = (t0 > 0.f) ? t0 : NEG_SLOPE * t0;
        t1 = (t1 > 0.f) ? t1 : NEG_SLOPE * t1;
        float p0 = __expf(fminf(t0, 80.f));
        float p1 = __expf(fminf(t1, 80.f));
        half8 a0 = *(const half8*)&xh[(size_t)u0 * IND + cg * 16];
        half8 b0 = *(const half8*)&xh[(size_t)u0 * IND + cg * 16 + 8];
        half8 a1 = *(const half8*)&xh[(size_t)u1 * IND + cg * 16];
        half8 b1 = *(const half8*)&xh[(size_t)u1 * IND + cg * 16 + 8];
        l += p0 + p1;
        #pragma unroll
        for (int j = 0; j < 8; j++) {
            acc[j]     = fmaf(p0, (float)a0[j], acc[j]);
            acc[j + 8] = fmaf(p0, (float)b0[j], acc[j + 8]);
            acc[j]     = fmaf(p1, (float)a1[j], acc[j]);
            acc[j + 8] = fmaf(p1, (float)b1[j], acc[j + 8]);
        }
    }
    if (i < s1) {
        int u0 = csr_src[i];
        float t0 = als[u0 * NHEADS + hd] + adst;
        t0 = (t0 > 0.f) ? t0 : NEG_SLOPE * t0;
        float p0 = __expf(fminf(t0, 80.f));
        half8 a0 = *(const half8*)&xh[(size_t)u0 * IND + cg * 16];
        half8 b0 = *(const half8*)&xh[(size_t)u0 * IND + cg * 16 + 8];
        l += p0;
        #pragma unroll
        for (int j = 0; j < 8; j++) {
            acc[j]     = fmaf(p0, (float)a0[j], acc[j]);
            acc[j + 8] = fmaf(p0, (float)b0[j], acc[j + 8]);
        }
    }
    float inv = 1.f / (l + 1e-16f);
    half8 o0, o1;
    #pragma unroll
    for (int j = 0; j < 8; j++) {
        o0[j] = (_Float16)(acc[j] * inv);
        o1[j] = (_Float16)(acc[j + 8] * inv);
    }
    size_t base = (size_t)v * (NHEADS * IND) + hd * IND + cg * 16;
    *(half8*)&xagg[base] = o0;
    *(half8*)&xagg[base + 8] = o1;
}

// ---------------- block-diagonal GEMM (layer 1): gact[:,h*64+*] = ELU(xagg[:,h,:]@W1_h + b1) ----
#define LDK 40
__global__ __launch_bounds__(256) void gemm1_bd(const _Float16* __restrict__ xagg,
                                                const _Float16* __restrict__ Bt,  // W1T [512][128]
                                                const float* __restrict__ bias,
                                                _Float16* __restrict__ gact,
                                                int M) {
    __shared__ _Float16 sA[64 * LDK];
    __shared__ _Float16 sB[64 * LDK];
    int tid = threadIdx.x;
    int lane = tid & 63;
    int wv = tid >> 6;           // wave owns 16 cols: wv*16
    int m0 = blockIdx.x * 64;
    int h = blockIdx.y;          // head / 64-col block
    int quad = lane >> 4;
    int l15 = lane & 15;
    int arow = tid >> 2;
    int ac4 = tid & 3;

    floatx4 acc[4] = {};

    for (int k0 = 0; k0 < IND; k0 += 32) {
        {
            int gm = m0 + arow;
            int4 va;
            if (gm < M) va = *(const int4*)&xagg[(size_t)gm * (NHEADS * IND) + h * IND + k0 + ac4 * 8];
            else        va = make_int4(0, 0, 0, 0);
            *(int4*)&sA[arow * LDK + ac4 * 8] = va;
            int gn = h * 64 + arow;   // W1T row (output col)
            int4 vb = *(const int4*)&Bt[(size_t)gn * IND + k0 + ac4 * 8];
            *(int4*)&sB[arow * LDK + ac4 * 8] = vb;
        }
        __syncthreads();
        half8 a[4], b;
        #pragma unroll
        for (int i = 0; i < 4; i++)
            a[i] = *(const half8*)&sA[(i * 16 + l15) * LDK + quad * 8];
        b = *(const half8*)&sB[(wv * 16 + l15) * LDK + quad * 8];
        #pragma unroll
        for (int i = 0; i < 4; i++)
            acc[i] = __builtin_amdgcn_mfma_f32_16x16x32_f16(a[i], b, acc[i], 0, 0, 0);
        __syncthreads();
    }
    // C/D layout: col = lane&15, row = quad*4 + reg
    #pragma unroll
    for (int i = 0; i < 4; i++) {
        #pragma unroll
        for (int r = 0; r < 4; r++) {
            int gm = m0 + i * 16 + quad * 4 + r;
            if (gm < M) {
                int col = h * 64 + wv * 16 + l15;
                float o = acc[i][r] + bias[col];
                o = (o > 0.f) ? o : (__expf(o) - 1.f);   // ELU
                gact[(size_t)gm * HCV + col] = (_Float16)o;
            }
        }
    }
}

// ---------------- MFMA GEMM 64x128 (layer 2): f16, fused al epilogue ----------------
__global__ __launch_bounds__(256) void gemm_l2(const _Float16* __restrict__ A,
                                               const _Float16* __restrict__ Bt,
                                               _Float16* __restrict__ C16,
                                               const float* __restrict__ a_src,
                                               const float* __restrict__ a_dst,
                                               float* __restrict__ als,
                                               float* __restrict__ ald,
                                               int M, int K) {
    __shared__ _Float16 sA[64 * LDK];
    __shared__ _Float16 sB[128 * LDK];
    __shared__ float psum_s[4][64];
    __shared__ float psum_d[4][64];
    int tid = threadIdx.x;
    int lane = tid & 63;
    int wv = tid >> 6;
    int m0 = blockIdx.x * 64, n0 = blockIdx.y * 128;
    int quad = lane >> 4;
    int l15 = lane & 15;
    int arow = tid >> 2;
    int ac4 = tid & 3;

    floatx4 acc[4][2] = {};

    for (int k0 = 0; k0 < K; k0 += 32) {
        {
            int gm = m0 + arow;
            int4 va;
            if (gm < M) va = *(const int4*)&A[(size_t)gm * K + k0 + ac4 * 8];
            else        va = make_int4(0, 0, 0, 0);
            *(int4*)&sA[arow * LDK + ac4 * 8] = va;
            #pragma unroll
            for (int r = 0; r < 2; r++) {
                int gn = n0 + arow + r * 64;
                int4 vb = *(const int4*)&Bt[(size_t)gn * K + k0 + ac4 * 8];
                *(int4*)&sB[(arow + r * 64) * LDK + ac4 * 8] = vb;
            }
        }
        __syncthreads();
        half8 a[4], b[2];
        #pragma unroll
        for (int i = 0; i < 4; i++)
            a[i] = *(const half8*)&sA[(i * 16 + l15) * LDK + quad * 8];
        #pragma unroll
        for (int j = 0; j < 2; j++)
            b[j] = *(const half8*)&sB[(wv * 32 + j * 16 + l15) * LDK + quad * 8];
        #pragma unroll
        for (int i = 0; i < 4; i++)
            #pragma unroll
            for (int j = 0; j < 2; j++)
                acc[i][j] = __builtin_amdgcn_mfma_f32_16x16x32_f16(a[i], b[j], acc[i][j], 0, 0, 0);
        __syncthreads();
    }
    #pragma unroll
    for (int i = 0; i < 4; i++) {
        #pragma unroll
        for (int r = 0; r < 4; r++) {
            int gm = m0 + i * 16 + quad * 4 + r;
            if (gm < M) {
                #pragma unroll
                for (int j = 0; j < 2; j++)
                    C16[(size_t)gm * HCV + n0 + wv * 32 + j * 16 + l15] = (_Float16)acc[i][j][r];
            }
        }
    }
    // fused half-logits: wave's 32 cols in one head
    int h0 = n0 >> 6;
    float as_v[2], ad_v[2];
    #pragma unroll
    for (int j = 0; j < 2; j++) {
        int dim = (wv * 32 + j * 16 + l15) & 63;
        int hh = h0 + (wv >> 1);
        as_v[j] = a_src[hh * HID + dim];
        ad_v[j] = a_dst[hh * HID + dim];
    }
    #pragma unroll
    for (int i = 0; i < 4; i++) {
        #pragma unroll
        for (int r = 0; r < 4; r++) {
            float ps = acc[i][0][r] * as_v[0] + acc[i][1][r] * as_v[1];
            float pd = acc[i][0][r] * ad_v[0] + acc[i][1][r] * ad_v[1];
            #pragma unroll
            for (int off = 1; off <= 8; off <<= 1) {
                ps += __shfl_xor(ps, off);
                pd += __shfl_xor(pd, off);
            }
            if (l15 == 0) {
                int row = i * 16 + quad * 4 + r;
                psum_s[wv][row] = ps;
                psum_d[wv][row] = pd;
            }
        }
    }
    __syncthreads();
    if (tid < 64) {
        int gm = m0 + tid;
        if (gm < M) {
            als[gm * NHEADS + h0]     = psum_s[0][tid] + psum_s[1][tid];
            als[gm * NHEADS + h0 + 1] = psum_s[2][tid] + psum_s[3][tid];
            ald[gm * NHEADS + h0]     = psum_d[0][tid] + psum_d[1][tid];
            ald[gm * NHEADS + h0 + 1] = psum_d[2][tid] + psum_d[3][tid];
        }
    }
}

// ---------------- MFMA GEMM 64x128 (layer 3): f16 C out, fused al3 ----------------
__global__ __launch_bounds__(256) void gemm3(const _Float16* __restrict__ A,
                                             const _Float16* __restrict__ Bt,
                                             _Float16* __restrict__ C16,
                                             const float* __restrict__ a_src,
                                             const float* __restrict__ a_dst,
                                             float* __restrict__ als,
                                             float* __restrict__ ald,
                                             int M, int K) {
    __shared__ _Float16 sA[64 * LDK];
    __shared__ _Float16 sB[128 * LDK];
    __shared__ float psum_s[4][64];
    __shared__ float psum_d[4][64];
    int tid = threadIdx.x;
    int lane = tid & 63;
    int wv = tid >> 6;
    int m0 = blockIdx.x * 64;
    int quad = lane >> 4;
    int l15 = lane & 15;
    int arow = tid >> 2;
    int ac4 = tid & 3;

    floatx4 acc[4][2] = {};

    for (int k0 = 0; k0 < K; k0 += 32) {
        {
            int gm = m0 + arow;
            int4 va;
            if (gm < M) va = *(const int4*)&A[(size_t)gm * K + k0 + ac4 * 8];
            else        va = make_int4(0, 0, 0, 0);
            *(int4*)&sA[arow * LDK + ac4 * 8] = va;
            #pragma unroll
            for (int r = 0; r < 2; r++) {
                int gn = arow + r * 64;
                int4 vb = *(const int4*)&Bt[(size_t)gn * K + k0 + ac4 * 8];
                *(int4*)&sB[(arow + r * 64) * LDK + ac4 * 8] = vb;
            }
        }
        __syncthreads();
        half8 a[4], b[2];
        #pragma unroll
        for (int i = 0; i < 4; i++)
            a[i] = *(const half8*)&sA[(i * 16 + l15) * LDK + quad * 8];
        #pragma unroll
        for (int j = 0; j < 2; j++)
            b[j] = *(const half8*)&sB[(wv * 32 + j * 16 + l15) * LDK + quad * 8];
        #pragma unroll
        for (int i = 0; i < 4; i++)
            #pragma unroll
            for (int j = 0; j < 2; j++)
                acc[i][j] = __builtin_amdgcn_mfma_f32_16x16x32_f16(a[i], b[j], acc[i][j], 0, 0, 0);
        __syncthreads();
    }
    #pragma unroll
    for (int i = 0; i < 4; i++) {
        #pragma unroll
        for (int r = 0; r < 4; r++) {
            int gm = m0 + i * 16 + quad * 4 + r;
            if (gm < M) {
                #pragma unroll
                for (int j = 0; j < 2; j++)
                    C16[(size_t)gm * OUTD + wv * 32 + j * 16 + l15] = (_Float16)acc[i][j][r];
            }
        }
    }
    float as_v[2], ad_v[2];
    #pragma unroll
    for (int j = 0; j < 2; j++) {
        as_v[j] = a_src[wv * 32 + j * 16 + l15];
        ad_v[j] = a_dst[wv * 32 + j * 16 + l15];
    }
    #pragma unroll
    for (int i = 0; i < 4; i++) {
        #pragma unroll
        for (int r = 0; r < 4; r++) {
            float ps = acc[i][0][r] * as_v[0] + acc[i][1][r] * as_v[1];
            float pd = acc[i][0][r] * ad_v[0] + acc[i][1][r] * ad_v[1];
            #pragma unroll
            for (int off = 1; off <= 8; off <<= 1) {
                ps += __shfl_xor(ps, off);
                pd += __shfl_xor(pd, off);
            }
            if (l15 == 0) {
                int row = i * 16 + quad * 4 + r;
                psum_s[wv][row] = ps;
                psum_d[wv][row] = pd;
            }
        }
    }
    __syncthreads();
    if (tid < 64) {
        int gm = m0 + tid;
        if (gm < M) {
            als[gm] = psum_s[0][tid] + psum_s[1][tid] + psum_s[2][tid] + psum_s[3][tid];
            ald[gm] = psum_d[0][tid] + psum_d[1][tid] + psum_d[2][tid] + psum_d[3][tid];
        }
    }
}

// ---------------- layer-2 gather (output-side, 512-dim fp16), unroll 4 ----------------
__global__ __launch_bounds__(256) void gather2_kernel(const _Float16* __restrict__ h,
                                                      const int* __restrict__ row_ptr,
                                                      const int* __restrict__ csr_src,
                                                      const float* __restrict__ als,
                                                      const float* __restrict__ ald,
                                                      const float* __restrict__ bias,
                                                      _Float16* __restrict__ gout) {
    int lane = threadIdx.x & 63;
    int v = blockIdx.x * 4 + (threadIdx.x >> 6);
    if (v >= NN) return;
    int hd = lane >> 3;
    float adst = ald[v * NHEADS + hd];
    int s0 = row_ptr[v], s1 = row_ptr[v + 1];
    float acc[8] = {};
    float l = 0.f;
    int i = s0;
    for (; i + 4 <= s1; i += 4) {
        int u0 = csr_src[i], u1 = csr_src[i + 1], u2 = csr_src[i + 2], u3 = csr_src[i + 3];
        float t0 = als[u0 * NHEADS + hd] + adst;
        float t1 = als[u1 * NHEADS + hd] + adst;
        float t2 = als[u2 * NHEADS + hd] + adst;
        float t3 = als[u3 * NHEADS + hd] + adst;
        t0 = (t0 > 0.f) ? t0 : NEG_SLOPE * t0;
        t1 = (t1 > 0.f) ? t1 : NEG_SLOPE * t1;
        t2 = (t2 > 0.f) ? t2 : NEG_SLOPE * t2;
        t3 = (t3 > 0.f) ? t3 : NEG_SLOPE * t3;
        float p0 = __expf(fminf(t0, 80.f));
        float p1 = __expf(fminf(t1, 80.f));
        float p2 = __expf(fminf(t2, 80.f));
        float p3 = __expf(fminf(t3, 80.f));
        half8 x0 = *(const half8*)&h[(size_t)u0 * HCV + lane * 8];
        half8 x1 = *(const half8*)&h[(size_t)u1 * HCV + lane * 8];
        half8 x2 = *(const half8*)&h[(size_t)u2 * HCV + lane * 8];
        half8 x3 = *(const half8*)&h[(size_t)u3 * HCV + lane * 8];
        l += (p0 + p1) + (p2 + p3);
        #pragma unroll
        for (int j = 0; j < 8; j++) {
            acc[j] = fmaf(p0, (float)x0[j], acc[j]);
            acc[j] = fmaf(p1, (float)x1[j], acc[j]);
            acc[j] = fmaf(p2, (float)x2[j], acc[j]);
            acc[j] = fmaf(p3, (float)x3[j], acc[j]);
        }
    }
    for (; i < s1; i++) {
        int u0 = csr_src[i];
        float t0 = als[u0 * NHEADS + hd] + adst;
        t0 = (t0 > 0.f) ? t0 : NEG_SLOPE * t0;
        float p0 = __expf(fminf(t0, 80.f));
        half8 x0 = *(const half8*)&h[(size_t)u0 * HCV + lane * 8];
        l += p0;
        #pragma unroll
        for (int j = 0; j < 8; j++)
            acc[j] = fmaf(p0, (float)x0[j], acc[j]);
    }
    float inv = 1.f / (l + 1e-16f);
    half8 hv;
    #pragma unroll
    for (int j = 0; j < 8; j++) {
        float o = fmaf(acc[j], inv, bias[lane * 8 + j]);
        o = (o > 0.f) ? o : (__expf(o) - 1.f);   // ELU
        hv[j] = (_Float16)o;
    }
    *(half8*)&gout[(size_t)v * HCV + lane * 8] = hv;
}

// ---------------- layer-3 gather (fp16 h3 -> fp32 out, with max pass) ----------------
__global__ __launch_bounds__(256) void gather3_kernel(const _Float16* __restrict__ h,
                                                      const int* __restrict__ row_ptr,
                                                      const int* __restrict__ csr_src,
                                                      const float* __restrict__ als,
                                                      const float* __restrict__ ald,
                                                      const float* __restrict__ bias,
                                                      float* __restrict__ out) {
    int lane = threadIdx.x & 63;
    int v = blockIdx.x * 4 + (threadIdx.x >> 6);
    if (v >= NN) return;
    int e_sub = lane >> 4;   // 0..3
    int cg = lane & 15;      // 8 ch: cg*8
    float adst = ald[v];
    int s0 = row_ptr[v], s1 = row_ptr[v + 1];
    float m = -INFINITY;
    for (int i = s0 + e_sub; i < s1; i += 4) {
        int u = csr_src[i];
        float t = als[u] + adst;
        t = (t > 0.f) ? t : NEG_SLOPE * t;
        m = fmaxf(m, t);
    }
    m = fmaxf(m, __shfl_xor(m, 16));
    m = fmaxf(m, __shfl_xor(m, 32));
    float acc[8] = {};
    float l = 0.f;
    for (int i = s0 + e_sub; i < s1; i += 4) {
        int u = csr_src[i];
        float t = als[u] + adst;
        t = (t > 0.f) ? t : NEG_SLOPE * t;
        float p = __expf(t - m);
        half8 x = *(const half8*)&h[(size_t)u * OUTD + cg * 8];
        l += p;
        #pragma unroll
        for (int j = 0; j < 8; j++)
            acc[j] = fmaf(p, (float)x[j], acc[j]);
    }
    l += __shfl_xor(l, 16);
    l += __shfl_xor(l, 32);
    #pragma unroll
    for (int j = 0; j < 8; j++) {
        acc[j] += __shfl_xor(acc[j], 16);
        acc[j] += __shfl_xor(acc[j], 32);
    }
    if (e_sub == 0) {
        float inv = 1.f / (l + 1e-16f);
        float4 o0, o1;
        o0.x = fmaf(acc[0], inv, bias[cg * 8 + 0]);
        o0.y = fmaf(acc[1], inv, bias[cg * 8 + 1]);
        o0.z = fmaf(acc[2], inv, bias[cg * 8 + 2]);
        o0.w = fmaf(acc[3], inv, bias[cg * 8 + 3]);
        o1.x = fmaf(acc[4], inv, bias[cg * 8 + 4]);
        o1.y = fmaf(acc[5], inv, bias[cg * 8 + 5]);
        o1.z = fmaf(acc[6], inv, bias[cg * 8 + 6]);
        o1.w = fmaf(acc[7], inv, bias[cg * 8 + 7]);
        *(float4*)&out[(size_t)v * OUTD + cg * 8] = o0;
        *(float4*)&out[(size_t)v * OUTD + cg * 8 + 4] = o1;
    }
}

// ---------------- launch ----------------

extern "C" void kernel_launch(void* const* d_in, const int* in_sizes, int n_in,
                              void* d_out, int out_size, void* d_ws, size_t ws_size,
                              hipStream_t stream) {
    const float* x     = (const float*)d_in[0];
    const int*   ei    = (const int*)d_in[1];
    const float* W1    = (const float*)d_in[2];
    const float* as1   = (const float*)d_in[3];
    const float* ad1   = (const float*)d_in[4];
    const float* b1    = (const float*)d_in[5];
    const float* W2    = (const float*)d_in[6];
    const float* as2   = (const float*)d_in[7];
    const float* ad2   = (const float*)d_in[8];
    const float* b2    = (const float*)d_in[9];
    const float* W3    = (const float*)d_in[10];
    const float* as3   = (const float*)d_in[11];
    const float* ad3   = (const float*)d_in[12];
    const float* b3    = (const float*)d_in[13];
    float* out = (float*)d_out;

    size_t off = 0;
    auto carve = [&](size_t bytes) {
        void* p = (char*)d_ws + off;
        off += (bytes + 255) & ~(size_t)255;
        return p;
    };
    int* row_ptr   = (int*)carve((NN + 1) * sizeof(int));
    int* cursor    = (int*)carve(NN * sizeof(int));
    int* csr_src   = (int*)carve(ETOT * sizeof(int));
    _Float16* xh   = (_Float16*)carve((size_t)NN * IND * sizeof(_Float16));        // x fp16
    _Float16* xagg = (_Float16*)carve((size_t)NN * NHEADS * IND * sizeof(_Float16)); // 41 MB
    _Float16* gact = (_Float16*)carve((size_t)NN * HCV * sizeof(_Float16));        // L1 out
    _Float16* hf16 = (_Float16*)carve((size_t)NN * HCV * sizeof(_Float16));        // h2
    _Float16* h3   = (_Float16*)carve((size_t)NN * OUTD * sizeof(_Float16));       // h3 fp16
    float* als     = (float*)carve((size_t)NN * NHEADS * sizeof(float));
    float* ald     = (float*)carve((size_t)NN * NHEADS * sizeof(float));
    float* w1p     = (float*)carve((size_t)IND * 16 * sizeof(float));
    _Float16* W1T  = (_Float16*)carve((size_t)S1 * sizeof(_Float16));
    _Float16* W2T  = (_Float16*)carve((size_t)S2 * sizeof(_Float16));
    _Float16* W3T  = (_Float16*)carve((size_t)S3 * sizeof(_Float16));
    // gact2 aliases xagg (dead after gemm1_bd)
    _Float16* gact2 = xagg;
    (void)ws_size; (void)n_in; (void)in_sizes; (void)out_size;

    dim3 blk(256);

    // ---- prep ----
    int prep_n = STOT + NN + XTOT + IND * 16;
    prep_kernel<<<(prep_n + 255) / 256, blk, 0, stream>>>(W1, W2, W3, x, as1, ad1,
        W1T, W2T, W3T, xh, w1p, cursor);

    // ---- CSR build ----
    count_kernel<<<(ETOT + 255) / 256, blk, 0, stream>>>(ei, cursor);
    scan_kernel<<<1, 1024, 0, stream>>>(cursor, row_ptr, cursor);
    fill_kernel<<<(ETOT + 255) / 256, blk, 0, stream>>>(ei, cursor, csr_src);

    int mt64 = (NN + 63) / 64;
    int nwaves_n = (NN + 3) / 4;

    // ---- layer 1: input-side aggregation ----
    al1_thin<<<(NN * 16 + 255) / 256, blk, 0, stream>>>(x, w1p, als, ald);
    gather1_kernel<<<nwaves_n, blk, 0, stream>>>(xh, row_ptr, csr_src, als, ald, xagg);
    gemm1_bd<<<dim3(mt64, NHEADS), blk, 0, stream>>>(xagg, W1T, b1, gact, NN);

    // ---- layer 2: output-side (unchanged structure) ----
    gemm_l2<<<dim3(mt64, HCV / 128), blk, 0, stream>>>(gact, W2T, hf16, as2, ad2, als, ald, NN, HCV);
    gather2_kernel<<<nwaves_n, blk, 0, stream>>>(hf16, row_ptr, csr_src, als, ald, b2, gact2);

    // ---- layer 3: output-side, fp16 h3 ----
    gemm3<<<dim3(mt64, 1), blk, 0, stream>>>(gact2, W3T, h3, as3, ad3, als, ald, NN, HCV);
    gather3_kernel<<<nwaves_n, blk, 0, stream>>>(h3, row_ptr, csr_src, als, ald, b3, out);
}